// Round 1
// baseline (399.793 us; speedup 1.0000x reference)
//
#include <hip/hip_runtime.h>
#include <math.h>

// Problem constants
#define T_LEN 131072
#define NCH   32
#define NBAT  4
#define WIN   512
#define HOP   256
#define NFR   512            // frames per (b,c) = T/HOP
#define NBIN  257            // rfft bins
#define OLEN  (NFR*HOP + HOP) // 131328 overlap-add length
#define NBC   (NBAT*NCH)     // 128

// ---------------------------------------------------------------------------
// 1) channel mix: y[b,d,t] = sum_c x[b,c,t] * mixer[c,d]
// ---------------------------------------------------------------------------
__global__ __launch_bounds__(256) void mix_kernel(const float* __restrict__ x,
                                                  const float* __restrict__ mixer,
                                                  float* __restrict__ y) {
  __shared__ float xs[NCH][256];
  __shared__ float mm[NCH][NCH];
  int b = blockIdx.y;
  int t = blockIdx.x * 256 + threadIdx.x;
  for (int i = threadIdx.x; i < NCH * NCH; i += 256)
    ((float*)mm)[i] = mixer[i];
  for (int c = 0; c < NCH; c++)
    xs[c][threadIdx.x] = x[((size_t)(b * NCH + c)) * T_LEN + t];
  __syncthreads();
  float xr[NCH];
#pragma unroll
  for (int c = 0; c < NCH; c++) xr[c] = xs[c][threadIdx.x];
#pragma unroll 4
  for (int d = 0; d < NCH; d++) {
    float acc = 0.f;
#pragma unroll
    for (int c = 0; c < NCH; c++) acc = fmaf(xr[c], mm[c][d], acc);
    y[((size_t)(b * NCH + d)) * T_LEN + t] = acc;
  }
}

// ---------------------------------------------------------------------------
// 256-pt complex Stockham FFT stage helper (in LDS, double-buffered).
// Per wave: lanes 0..63, each does 2 butterflies per stage, 8 stages.
// Reads buf[cur], writes buf[cur^1]; barrier between stages.
// ---------------------------------------------------------------------------
__device__ __forceinline__ void fft256(float2 (*buf)[256], int lane) {
  int cur = 0;
#pragma unroll
  for (int st = 0; st < 8; st++) {
    int s = 1 << st;
    int nn = 256 >> st;
    float w0 = -6.28318530717958647692f / (float)nn;
#pragma unroll
    for (int j = 0; j < 2; j++) {
      int i = lane + 64 * j;          // 0..127 butterfly index
      int p = i >> st;
      float2 a = buf[cur][i];
      float2 b = buf[cur][i + 128];
      float ang = w0 * (float)p;
      float sw, cw;
      __sincosf(ang, &sw, &cw);
      float2 apb = make_float2(a.x + b.x, a.y + b.y);
      float2 amb = make_float2(a.x - b.x, a.y - b.y);
      float2 tw  = make_float2(amb.x * cw - amb.y * sw,
                               amb.x * sw + amb.y * cw);
      int o = i + s * p;
      buf[cur ^ 1][o]     = apb;
      buf[cur ^ 1][o + s] = tw;
    }
    cur ^= 1;
    __syncthreads();
  }
  // result ends in buf[0] (8 toggles)
}

// ---------------------------------------------------------------------------
// 2) forward rfft(512) per frame via packed 256-pt complex FFT + untangle
// ---------------------------------------------------------------------------
__global__ __launch_bounds__(256) void fft_fwd_kernel(const float* __restrict__ y,
                                                      float2* __restrict__ spec) {
  __shared__ float2 lds[4][2][256];
  int wave = threadIdx.x >> 6, lane = threadIdx.x & 63;
  int fid = blockIdx.x * 4 + wave;    // 0..65535
  int bc = fid >> 9, f = fid & (NFR - 1);
  const float* src = y + (size_t)bc * T_LEN + (size_t)f * HOP;
  // pack z[n] = y[2n] + i*y[2n+1]; last frame's top half is zero padding
#pragma unroll
  for (int j = 0; j < 4; j++) {
    int n = lane + 64 * j;
    float2 v = make_float2(0.f, 0.f);
    if (!(f == NFR - 1 && n >= 128)) v = *(const float2*)(src + 2 * n);
    lds[wave][0][n] = v;
  }
  __syncthreads();
  fft256(lds[wave], lane);
  // untangle: Y[k] = E[k] + W^k O[k], W = e^{-2*pi*i/512}
  const float2* Z = lds[wave][0];
#pragma unroll
  for (int j = 0; j < 5; j++) {
    int k = lane + 64 * j;
    if (k <= 256) {
      float2 zk  = Z[k & 255];
      float2 zmk = Z[(256 - k) & 255];
      float Ex = 0.5f * (zk.x + zmk.x), Ey = 0.5f * (zk.y - zmk.y);
      float dx = 0.5f * (zk.x - zmk.x), dy = 0.5f * (zk.y + zmk.y);
      float Ox = dy, Oy = -dx;   // O = -i*(dx + i*dy)
      float ang = -6.28318530717958647692f * (float)k / 512.0f;
      float sw, cw;
      __sincosf(ang, &sw, &cw);
      float Yx = Ex + Ox * cw - Oy * sw;
      float Yy = Ey + Ox * sw + Oy * cw;
      spec[(size_t)fid * NBIN + k] = make_float2(Yx, Yy);
    }
  }
}

// ---------------------------------------------------------------------------
// 3) per-bin IIR scan over frames: O[f] = tr * (S[f] + O[f-1]), in place
// ---------------------------------------------------------------------------
__global__ __launch_bounds__(256) void scan_kernel(float2* __restrict__ spec,
                                                   const float* __restrict__ transfer) {
  int tid = blockIdx.x * 256 + threadIdx.x;
  if (tid >= NBC * NBIN) return;
  int bc = tid / NBIN, k = tid - bc * NBIN;
  int c = bc & (NCH - 1);
  float tr = transfer[c * NBIN + k];
  float2* p = spec + (size_t)bc * NFR * NBIN + k;
  float sx = 0.f, sy = 0.f;
  for (int f = 0; f < NFR; f += 8) {
    float2 v[8];
#pragma unroll
    for (int u = 0; u < 8; u++) v[u] = p[(size_t)u * NBIN];
#pragma unroll
    for (int u = 0; u < 8; u++) {
      sx = tr * (v[u].x + sx);
      sy = tr * (v[u].y + sy);
      p[(size_t)u * NBIN] = make_float2(sx, sy);
    }
    p += (size_t)8 * NBIN;
  }
}

// ---------------------------------------------------------------------------
// 4) inverse rfft per frame + hann + overlap-add (atomic) into acc
// ---------------------------------------------------------------------------
__global__ __launch_bounds__(256) void fft_inv_kernel(const float2* __restrict__ spec,
                                                      float* __restrict__ acc) {
  __shared__ float2 lds[4][2][256];
  __shared__ float2 yb[4][NBIN];
  int wave = threadIdx.x >> 6, lane = threadIdx.x & 63;
  int fid = blockIdx.x * 4 + wave;
  int bc = fid >> 9, f = fid & (NFR - 1);
  const float2* sp = spec + (size_t)fid * NBIN;
#pragma unroll
  for (int j = 0; j < 5; j++) {
    int k = lane + 64 * j;
    if (k <= 256) yb[wave][k] = sp[k];
  }
  __syncthreads();
  // inverse untangle: Z[k] = E[k] + i*O[k]; store conj(Z) for ifft-via-fft
#pragma unroll
  for (int j = 0; j < 4; j++) {
    int k = lane + 64 * j;          // 0..255
    float2 yk  = yb[wave][k];
    float2 ymk = yb[wave][256 - k];
    float Ex = 0.5f * (yk.x + ymk.x), Ey = 0.5f * (yk.y - ymk.y);
    float dx = 0.5f * (yk.x - ymk.x), dy = 0.5f * (yk.y + ymk.y);
    float ang = 6.28318530717958647692f * (float)k / 512.0f;
    float sw, cw;
    __sincosf(ang, &sw, &cw);
    float Ox = dx * cw - dy * sw, Oy = dx * sw + dy * cw;
    lds[wave][0][k] = make_float2(Ex - Oy, -(Ey + Ox));
  }
  __syncthreads();
  fft256(lds[wave], lane);
  // z[n] = conj(R[n])/256 ; y[2n]=Re, y[2n+1]=Im ; then hann + OLA
  size_t base = (size_t)bc * OLEN + (size_t)f * HOP;
#pragma unroll
  for (int j = 0; j < 4; j++) {
    int n = lane + 64 * j;
    float2 r = lds[wave][0][n];
    float y0 = r.x * (1.0f / 256.0f);
    float y1 = -r.y * (1.0f / 256.0f);
    int t0 = 2 * n;
    float h0 = 0.5f - 0.5f * __cosf((float)t0 * (6.28318530717958647692f / 512.f));
    float h1 = 0.5f - 0.5f * __cosf((float)(t0 + 1) * (6.28318530717958647692f / 512.f));
    atomicAdd(&acc[base + t0],     y0 * h0);
    atomicAdd(&acc[base + t0 + 1], y1 * h1);
  }
}

// ---------------------------------------------------------------------------
// 5) out = tanh(gain * acc), truncated to T
// ---------------------------------------------------------------------------
__global__ __launch_bounds__(256) void final_kernel(const float* __restrict__ acc,
                                                    const float* __restrict__ gain,
                                                    float* __restrict__ out) {
  int bc = blockIdx.y;
  int c = bc & (NCH - 1);
  int t = blockIdx.x * 256 + threadIdx.x;
  float g = gain[c];
  float v = acc[(size_t)bc * OLEN + t];
  out[(size_t)bc * T_LEN + t] = tanhf(g * v);
}

// ---------------------------------------------------------------------------
extern "C" void kernel_launch(void* const* d_in, const int* in_sizes, int n_in,
                              void* d_out, int out_size, void* d_ws, size_t ws_size,
                              hipStream_t stream) {
  (void)in_sizes; (void)n_in; (void)out_size; (void)ws_size;
  const float* x        = (const float*)d_in[0];
  const float* transfer = (const float*)d_in[1];
  const float* mixer    = (const float*)d_in[2];
  const float* gain     = (const float*)d_in[3];
  float* out = (float*)d_out;

  // workspace layout: [spec: NBC*NFR*NBIN float2][acc: NBC*OLEN float]
  // mixed signal y aliases acc (y is dead before acc is zeroed).
  float2* spec = (float2*)d_ws;
  size_t spec_bytes = (size_t)NBC * NFR * NBIN * sizeof(float2); // ~134.5 MB
  float* acc = (float*)((char*)d_ws + spec_bytes);               // ~67.2 MB
  float* y = acc;

  mix_kernel<<<dim3(T_LEN / 256, NBAT), 256, 0, stream>>>(x, mixer, y);
  fft_fwd_kernel<<<dim3(NBC * NFR / 4), 256, 0, stream>>>(y, spec);
  scan_kernel<<<dim3((NBC * NBIN + 255) / 256), 256, 0, stream>>>(spec, transfer);
  hipMemsetAsync(acc, 0, (size_t)NBC * OLEN * sizeof(float), stream);
  fft_inv_kernel<<<dim3(NBC * NFR / 4), 256, 0, stream>>>(spec, acc);
  final_kernel<<<dim3(T_LEN / 256, NBC), 256, 0, stream>>>(acc, gain, out);
}

// Round 2
// 219.599 us; speedup vs baseline: 1.8206x; 1.8206x over previous
//
#include <hip/hip_runtime.h>
#include <math.h>

// Problem constants
#define T_LEN 131072
#define NCH   32
#define NBAT  4
#define WIN   512
#define HOP   256
#define NFR   512            // frames per (b,c) = T/HOP
#define NBIN  257            // rfft bins
#define NBC   (NBAT*NCH)     // 128
#define FPB   4              // frames per block (fwd + inv)
#define NBLK  (NFR/FPB)      // 128 blocks per bc

// ---------------------------------------------------------------------------
// 1) channel mix: y[b,d,t] = sum_c x[b,c,t] * mixer[c,d]
// ---------------------------------------------------------------------------
__global__ __launch_bounds__(256) void mix_kernel(const float* __restrict__ x,
                                                  const float* __restrict__ mixer,
                                                  float* __restrict__ y) {
  __shared__ float xs[NCH][256];
  __shared__ float mm[NCH][NCH];
  int b = blockIdx.y;
  int t = blockIdx.x * 256 + threadIdx.x;
  for (int i = threadIdx.x; i < NCH * NCH; i += 256)
    ((float*)mm)[i] = mixer[i];
  for (int c = 0; c < NCH; c++)
    xs[c][threadIdx.x] = x[((size_t)(b * NCH + c)) * T_LEN + t];
  __syncthreads();
  float xr[NCH];
#pragma unroll
  for (int c = 0; c < NCH; c++) xr[c] = xs[c][threadIdx.x];
#pragma unroll 4
  for (int d = 0; d < NCH; d++) {
    float acc = 0.f;
#pragma unroll
    for (int c = 0; c < NCH; c++) acc = fmaf(xr[c], mm[c][d], acc);
    y[((size_t)(b * NCH + d)) * T_LEN + t] = acc;
  }
}

// ---------------------------------------------------------------------------
// 256-pt complex Stockham FFT (per-wave, LDS double-buffered)
// ---------------------------------------------------------------------------
__device__ __forceinline__ void fft256(float2 (*buf)[256], int lane) {
  int cur = 0;
#pragma unroll
  for (int st = 0; st < 8; st++) {
    int s = 1 << st;
    int nn = 256 >> st;
    float w0 = -6.28318530717958647692f / (float)nn;
#pragma unroll
    for (int j = 0; j < 2; j++) {
      int i = lane + 64 * j;          // 0..127 butterfly index
      int p = i >> st;
      float2 a = buf[cur][i];
      float2 b = buf[cur][i + 128];
      float ang = w0 * (float)p;
      float sw, cw;
      __sincosf(ang, &sw, &cw);
      float2 apb = make_float2(a.x + b.x, a.y + b.y);
      float2 amb = make_float2(a.x - b.x, a.y - b.y);
      float2 tw  = make_float2(amb.x * cw - amb.y * sw,
                               amb.x * sw + amb.y * cw);
      int o = i + s * p;
      buf[cur ^ 1][o]     = apb;
      buf[cur ^ 1][o + s] = tw;
    }
    cur ^= 1;
    __syncthreads();
  }
}

// ---------------------------------------------------------------------------
// 2) forward rfft(512): block = 4 consecutive frames of one bc.
//    Shared input staging (1280 samples covers 4 overlapped frames).
// ---------------------------------------------------------------------------
__global__ __launch_bounds__(256) void fft_fwd_kernel(const float* __restrict__ y,
                                                      float2* __restrict__ spec) {
  __shared__ float xin[FPB * HOP + WIN];          // 1280 floats
  __shared__ float2 lds[FPB][2][256];
  int wave = threadIdx.x >> 6, lane = threadIdx.x & 63;
  int bc = blockIdx.y, blk = blockIdx.x;
  size_t ybase = (size_t)bc * T_LEN + (size_t)blk * (FPB * HOP);
#pragma unroll
  for (int it = 0; it < 5; it++) {
    int i = it * 256 + threadIdx.x;
    int pos = blk * (FPB * HOP) + i;
    xin[i] = (pos < T_LEN) ? y[ybase + i] : 0.f;
  }
  __syncthreads();
  // pack z[n] = y[2n] + i*y[2n+1]
#pragma unroll
  for (int j = 0; j < 4; j++) {
    int n = lane + 64 * j;
    lds[wave][0][n] = make_float2(xin[wave * HOP + 2 * n],
                                  xin[wave * HOP + 2 * n + 1]);
  }
  __syncthreads();
  fft256(lds[wave], lane);
  // untangle: Y[k] = E[k] + W^k O[k], W = e^{-2*pi*i/512}
  const float2* Z = lds[wave][0];
  int fid = (bc * NFR) + blk * FPB + wave;
#pragma unroll
  for (int j = 0; j < 5; j++) {
    int k = lane + 64 * j;
    if (k <= 256) {
      float2 zk  = Z[k & 255];
      float2 zmk = Z[(256 - k) & 255];
      float Ex = 0.5f * (zk.x + zmk.x), Ey = 0.5f * (zk.y - zmk.y);
      float dx = 0.5f * (zk.x - zmk.x), dy = 0.5f * (zk.y + zmk.y);
      float Ox = dy, Oy = -dx;   // O = -i*(dx + i*dy)
      float ang = -6.28318530717958647692f * (float)k / 512.0f;
      float sw, cw;
      __sincosf(ang, &sw, &cw);
      float Yx = Ex + Ox * cw - Oy * sw;
      float Yy = Ey + Ox * sw + Oy * cw;
      spec[(size_t)fid * NBIN + k] = make_float2(Yx, Yy);
    }
  }
}

// ---------------------------------------------------------------------------
// 3) per-bin IIR scan over frames: O[f] = tr * (S[f] + O[f-1]), in place
// ---------------------------------------------------------------------------
__global__ __launch_bounds__(256) void scan_kernel(float2* __restrict__ spec,
                                                   const float* __restrict__ transfer) {
  int tid = blockIdx.x * 256 + threadIdx.x;
  if (tid >= NBC * NBIN) return;
  int bc = tid / NBIN, k = tid - bc * NBIN;
  int c = bc & (NCH - 1);
  float tr = transfer[c * NBIN + k];
  float2* p = spec + (size_t)bc * NFR * NBIN + k;
  float sx = 0.f, sy = 0.f;
  for (int f = 0; f < NFR; f += 8) {
    float2 v[8];
#pragma unroll
    for (int u = 0; u < 8; u++) v[u] = p[(size_t)u * NBIN];
#pragma unroll
    for (int u = 0; u < 8; u++) {
      sx = tr * (v[u].x + sx);
      sy = tr * (v[u].y + sy);
      p[(size_t)u * NBIN] = make_float2(sx, sy);
    }
    p += (size_t)8 * NBIN;
  }
}

// ---------------------------------------------------------------------------
// 4) inverse rfft + hann, block = 4 consecutive frames of one bc.
//    Block-local overlap-add: 3 interior chunks -> tanh -> out directly,
//    2 boundary half-windows -> bnd side buffer (no atomics anywhere).
// ---------------------------------------------------------------------------
__global__ __launch_bounds__(256) void fft_inv_kernel(const float2* __restrict__ spec,
                                                      const float* __restrict__ gain,
                                                      float* __restrict__ out,
                                                      float* __restrict__ bnd) {
  __shared__ float2 lds[FPB][2][256];
  __shared__ float2 yb[FPB][NBIN];
  __shared__ float wout[FPB][WIN];
  int wave = threadIdx.x >> 6, lane = threadIdx.x & 63;
  int bc = blockIdx.y, blk = blockIdx.x;
  int f = blk * FPB + wave;
  const float2* sp = spec + ((size_t)bc * NFR + f) * NBIN;
#pragma unroll
  for (int j = 0; j < 5; j++) {
    int k = lane + 64 * j;
    if (k <= 256) yb[wave][k] = sp[k];
  }
  __syncthreads();
  // inverse untangle: Z[k] = E[k] + i*O[k]; store conj(Z) for ifft-via-fft
#pragma unroll
  for (int j = 0; j < 4; j++) {
    int k = lane + 64 * j;          // 0..255
    float2 yk  = yb[wave][k];
    float2 ymk = yb[wave][256 - k];
    float Ex = 0.5f * (yk.x + ymk.x), Ey = 0.5f * (yk.y - ymk.y);
    float dx = 0.5f * (yk.x - ymk.x), dy = 0.5f * (yk.y + ymk.y);
    float ang = 6.28318530717958647692f * (float)k / 512.0f;
    float sw, cw;
    __sincosf(ang, &sw, &cw);
    float Ox = dx * cw - dy * sw, Oy = dx * sw + dy * cw;
    lds[wave][0][k] = make_float2(Ex - Oy, -(Ey + Ox));
  }
  __syncthreads();
  fft256(lds[wave], lane);
  // z[n] = conj(R[n])/256 ; y[2n]=Re, y[2n+1]=Im ; apply hann, stage in LDS
#pragma unroll
  for (int j = 0; j < 4; j++) {
    int n = lane + 64 * j;
    float2 r = lds[wave][0][n];
    float y0 = r.x * (1.0f / 256.0f);
    float y1 = -r.y * (1.0f / 256.0f);
    int t0 = 2 * n;
    float h0 = 0.5f - 0.5f * __cosf((float)t0 * (6.28318530717958647692f / 512.f));
    float h1 = 0.5f - 0.5f * __cosf((float)(t0 + 1) * (6.28318530717958647692f / 512.f));
    wout[wave][t0]     = y0 * h0;
    wout[wave][t0 + 1] = y1 * h1;
  }
  __syncthreads();
  float g = gain[bc & (NCH - 1)];
  // interior chunks m=1..3: frame(m-1) tail + frame(m) head -> tanh -> out
  size_t obase = (size_t)bc * T_LEN + (size_t)blk * (FPB * HOP);
#pragma unroll
  for (int it = 0; it < 3; it++) {
    int idx = it * 256 + threadIdx.x;       // 0..767
    int m = (idx >> 8) + 1, s = idx & 255;
    float v = wout[m - 1][HOP + s] + wout[m][s];
    out[obase + m * HOP + s] = tanhf(g * v);
  }
  // boundary halves -> side buffer: [bc][blk][2][HOP]
  float* bp = bnd + (((size_t)bc * NBLK + blk) * 2) * HOP;
  bp[threadIdx.x]       = wout[0][threadIdx.x];          // leading head (chunk 4*blk)
  bp[HOP + threadIdx.x] = wout[FPB - 1][HOP + threadIdx.x]; // trailing tail (chunk 4*blk+4)
}

// ---------------------------------------------------------------------------
// 5) combine boundary chunks: chunk 4b <- bnd[b-1].tail + bnd[b].head
// ---------------------------------------------------------------------------
__global__ __launch_bounds__(256) void final_kernel(const float* __restrict__ bnd,
                                                    const float* __restrict__ gain,
                                                    float* __restrict__ out) {
  int bc = blockIdx.y, b = blockIdx.x;
  int s = threadIdx.x;
  const float* base = bnd + ((size_t)bc * NBLK) * 2 * HOP;
  float v = base[((size_t)b * 2) * HOP + s];                       // head of block b
  if (b > 0) v += base[((size_t)(b - 1) * 2 + 1) * HOP + s];       // tail of block b-1
  float g = gain[bc & (NCH - 1)];
  out[(size_t)bc * T_LEN + (size_t)b * (FPB * HOP) + s] = tanhf(g * v);
}

// ---------------------------------------------------------------------------
extern "C" void kernel_launch(void* const* d_in, const int* in_sizes, int n_in,
                              void* d_out, int out_size, void* d_ws, size_t ws_size,
                              hipStream_t stream) {
  (void)in_sizes; (void)n_in; (void)out_size; (void)ws_size;
  const float* x        = (const float*)d_in[0];
  const float* transfer = (const float*)d_in[1];
  const float* mixer    = (const float*)d_in[2];
  const float* gain     = (const float*)d_in[3];
  float* out = (float*)d_out;

  // workspace layout: [spec: NBC*NFR*NBIN float2 ~134.5MB][y: NBC*T floats ~67MB]
  // bnd (33.5MB) aliases y (dead after fft_fwd).
  float2* spec = (float2*)d_ws;
  size_t spec_bytes = (size_t)NBC * NFR * NBIN * sizeof(float2);
  float* y   = (float*)((char*)d_ws + spec_bytes);
  float* bnd = y;

  mix_kernel<<<dim3(T_LEN / 256, NBAT), 256, 0, stream>>>(x, mixer, y);
  fft_fwd_kernel<<<dim3(NBLK, NBC), 256, 0, stream>>>(y, spec);
  scan_kernel<<<dim3((NBC * NBIN + 255) / 256), 256, 0, stream>>>(spec, transfer);
  fft_inv_kernel<<<dim3(NBLK, NBC), 256, 0, stream>>>(spec, gain, out, bnd);
  final_kernel<<<dim3(NBLK, NBC), 256, 0, stream>>>(bnd, gain, out);
}

// Round 3
// 197.846 us; speedup vs baseline: 2.0207x; 1.1100x over previous
//
#include <hip/hip_runtime.h>
#include <math.h>

// Problem constants
#define T_LEN 131072
#define NCH   32
#define NBAT  4
#define WIN   512
#define HOP   256
#define NFR   512            // frames per (b,c) = T/HOP
#define NBIN  257            // rfft bins
#define NBC   (NBAT*NCH)     // 128
#define FPB   4              // frames per block (fwd + inv)
#define NBLK  (NFR/FPB)      // 128 blocks per bc
#define TWOPI 6.28318530717958647692f

// XOR swizzle for FFT LDS arrays (float2 elements): bank-conflict-free for
// all radix-4 Stockham read/write strides. Applied to LOGICAL index on both
// read and write sides everywhere.
#define SWZ(m) ((m) ^ ((((m) >> 4) & 15)))

__device__ __forceinline__ float2 cmul(float2 u, float2 v) {
  return make_float2(fmaf(u.x, v.x, -u.y * v.y), fmaf(u.x, v.y, u.y * v.x));
}

// ---------------------------------------------------------------------------
// 1) channel mix: y[b,d,t] = sum_c x[b,c,t] * mixer[c,d]
// ---------------------------------------------------------------------------
__global__ __launch_bounds__(256) void mix_kernel(const float* __restrict__ x,
                                                  const float* __restrict__ mixer,
                                                  float* __restrict__ y) {
  __shared__ float xs[NCH][256];
  __shared__ float mm[NCH][NCH];
  int b = blockIdx.y;
  int t = blockIdx.x * 256 + threadIdx.x;
  for (int i = threadIdx.x; i < NCH * NCH; i += 256)
    ((float*)mm)[i] = mixer[i];
  for (int c = 0; c < NCH; c++)
    xs[c][threadIdx.x] = x[((size_t)(b * NCH + c)) * T_LEN + t];
  __syncthreads();
  float xr[NCH];
#pragma unroll
  for (int c = 0; c < NCH; c++) xr[c] = xs[c][threadIdx.x];
#pragma unroll 4
  for (int d = 0; d < NCH; d++) {
    float acc = 0.f;
#pragma unroll
    for (int c = 0; c < NCH; c++) acc = fmaf(xr[c], mm[c][d], acc);
    y[((size_t)(b * NCH + d)) * T_LEN + t] = acc;
  }
}

// ---------------------------------------------------------------------------
// 256-pt complex Stockham radix-4 FFT (per-wave, LDS double-buffered,
// table twiddles, XOR-swizzled). 4 stages, result lands in buf[0].
// Forward transform (exp(-2*pi*i/N)).
// ---------------------------------------------------------------------------
__device__ __forceinline__ void fft256_r4(float2 (*buf)[256],
                                          const float2* __restrict__ W256s,
                                          int lane) {
  int cur = 0;
#pragma unroll
  for (int st = 0; st < 4; st++) {
    int s = 1 << (2 * st);
    int p = lane >> (2 * st);
    float2 a = buf[cur][SWZ(lane)];
    float2 b = buf[cur][SWZ(lane + 64)];
    float2 c = buf[cur][SWZ(lane + 128)];
    float2 d = buf[cur][SWZ(lane + 192)];
    float2 w1 = W256s[p * s];      // exp(-2*pi*i * p / (256>>2st))
    float2 w2 = cmul(w1, w1);
    float2 w3 = cmul(w1, w2);
    float2 apc = make_float2(a.x + c.x, a.y + c.y);
    float2 amc = make_float2(a.x - c.x, a.y - c.y);
    float2 bpd = make_float2(b.x + d.x, b.y + d.y);
    float2 bmd = make_float2(b.x - d.x, b.y - d.y);
    float2 y0 = make_float2(apc.x + bpd.x, apc.y + bpd.y);
    float2 t1 = make_float2(amc.x + bmd.y, amc.y - bmd.x);  // amc - i*bmd
    float2 t2 = make_float2(apc.x - bpd.x, apc.y - bpd.y);
    float2 t3 = make_float2(amc.x - bmd.y, amc.y + bmd.x);  // amc + i*bmd
    int o = lane + 3 * s * p;
    buf[cur ^ 1][SWZ(o)]         = y0;
    buf[cur ^ 1][SWZ(o + s)]     = cmul(w1, t1);
    buf[cur ^ 1][SWZ(o + 2 * s)] = cmul(w2, t2);
    buf[cur ^ 1][SWZ(o + 3 * s)] = cmul(w3, t3);
    cur ^= 1;
    __syncthreads();
  }
}

// builds W256s[64] (exp(-2pi i m/256)) and W512s[257] (exp(-2pi i k/512))
__device__ __forceinline__ void build_tables(float2* W256s, float2* W512s) {
  int tid = threadIdx.x;
  if (tid < 64) {
    float sv, cv;
    __sincosf(-TWOPI * (float)tid * (1.0f / 256.0f), &sv, &cv);
    W256s[tid] = make_float2(cv, sv);
  }
  {
    float sv, cv;
    __sincosf(-TWOPI * (float)tid * (1.0f / 512.0f), &sv, &cv);
    W512s[tid] = make_float2(cv, sv);
    if (tid == 0) W512s[256] = make_float2(-1.f, 0.f);
  }
}

// ---------------------------------------------------------------------------
// 2) forward rfft(512): block = 4 consecutive frames of one bc.
// ---------------------------------------------------------------------------
__global__ __launch_bounds__(256) void fft_fwd_kernel(const float* __restrict__ y,
                                                      float2* __restrict__ spec) {
  __shared__ float xin[FPB * HOP + WIN];          // 1280 floats
  __shared__ float2 lds[FPB][2][256];
  __shared__ float2 W256s[64];
  __shared__ float2 W512s[NBIN];
  build_tables(W256s, W512s);
  int wave = threadIdx.x >> 6, lane = threadIdx.x & 63;
  int bc = blockIdx.y, blk = blockIdx.x;
  size_t ybase = (size_t)bc * T_LEN + (size_t)blk * (FPB * HOP);
#pragma unroll
  for (int it = 0; it < 5; it++) {
    int i = it * 256 + threadIdx.x;
    int pos = blk * (FPB * HOP) + i;
    xin[i] = (pos < T_LEN) ? y[ybase + i] : 0.f;
  }
  __syncthreads();
  // pack z[n] = y[2n] + i*y[2n+1]
#pragma unroll
  for (int j = 0; j < 4; j++) {
    int n = lane + 64 * j;
    lds[wave][0][SWZ(n)] = make_float2(xin[wave * HOP + 2 * n],
                                       xin[wave * HOP + 2 * n + 1]);
  }
  __syncthreads();
  fft256_r4(lds[wave], W256s, lane);
  // untangle: Y[k] = E[k] + W^k O[k], W = e^{-2*pi*i/512}
  const float2* Z = lds[wave][0];
  int fid = (bc * NFR) + blk * FPB + wave;
#pragma unroll
  for (int j = 0; j < 5; j++) {
    int k = lane + 64 * j;
    if (k <= 256) {
      float2 zk  = Z[SWZ(k & 255)];
      float2 zmk = Z[SWZ((256 - k) & 255)];
      float Ex = 0.5f * (zk.x + zmk.x), Ey = 0.5f * (zk.y - zmk.y);
      float dx = 0.5f * (zk.x - zmk.x), dy = 0.5f * (zk.y + zmk.y);
      float Ox = dy, Oy = -dx;   // O = -i*(dx + i*dy)
      float cw = W512s[k].x, sw = W512s[k].y;
      float Yx = Ex + Ox * cw - Oy * sw;
      float Yy = Ey + Ox * sw + Oy * cw;
      spec[(size_t)fid * NBIN + k] = make_float2(Yx, Yy);
    }
  }
}

// ---------------------------------------------------------------------------
// 3) per-bin IIR scan over frames: O[f] = tr * (S[f] + O[f-1]), in place
// ---------------------------------------------------------------------------
__global__ __launch_bounds__(256) void scan_kernel(float2* __restrict__ spec,
                                                   const float* __restrict__ transfer) {
  int tid = blockIdx.x * 256 + threadIdx.x;
  if (tid >= NBC * NBIN) return;
  int bc = tid / NBIN, k = tid - bc * NBIN;
  int c = bc & (NCH - 1);
  float tr = transfer[c * NBIN + k];
  float2* p = spec + (size_t)bc * NFR * NBIN + k;
  float sx = 0.f, sy = 0.f;
  for (int f = 0; f < NFR; f += 8) {
    float2 v[8];
#pragma unroll
    for (int u = 0; u < 8; u++) v[u] = p[(size_t)u * NBIN];
#pragma unroll
    for (int u = 0; u < 8; u++) {
      sx = tr * (v[u].x + sx);
      sy = tr * (v[u].y + sy);
      p[(size_t)u * NBIN] = make_float2(sx, sy);
    }
    p += (size_t)8 * NBIN;
  }
}

// ---------------------------------------------------------------------------
// 4) inverse rfft + hann, block = 4 consecutive frames of one bc.
//    Block-local overlap-add; boundary halves to side buffer. No atomics.
// ---------------------------------------------------------------------------
__global__ __launch_bounds__(256) void fft_inv_kernel(const float2* __restrict__ spec,
                                                      const float* __restrict__ gain,
                                                      float* __restrict__ out,
                                                      float* __restrict__ bnd) {
  __shared__ float2 lds[FPB][2][256];
  // yb is dead before w2 is first written (untangle reads precede the
  // pre-fft __syncthreads; w2 writes follow fft256_r4's internal barriers).
  __shared__ union {
    float2 yb[FPB][NBIN];
    float2 w2[FPB][256];
  } u;
  __shared__ float2 W256s[64];
  __shared__ float2 W512s[NBIN];
  build_tables(W256s, W512s);
  int wave = threadIdx.x >> 6, lane = threadIdx.x & 63;
  int bc = blockIdx.y, blk = blockIdx.x;
  int f = blk * FPB + wave;
  const float2* sp = spec + ((size_t)bc * NFR + f) * NBIN;
#pragma unroll
  for (int j = 0; j < 5; j++) {
    int k = lane + 64 * j;
    if (k <= 256) u.yb[wave][k] = sp[k];
  }
  __syncthreads();
  // inverse untangle: Z[k] = E[k] + i*O[k]; store conj(Z) for ifft-via-fft
#pragma unroll
  for (int j = 0; j < 4; j++) {
    int k = lane + 64 * j;          // 0..255
    float2 yk  = u.yb[wave][k];
    float2 ymk = u.yb[wave][256 - k];
    float Ex = 0.5f * (yk.x + ymk.x), Ey = 0.5f * (yk.y - ymk.y);
    float dx = 0.5f * (yk.x - ymk.x), dy = 0.5f * (yk.y + ymk.y);
    float cw = W512s[k].x, sw = -W512s[k].y;   // exp(+2pi i k/512)
    float Ox = dx * cw - dy * sw, Oy = dx * sw + dy * cw;
    lds[wave][0][SWZ(k)] = make_float2(Ex - Oy, -(Ey + Ox));
  }
  __syncthreads();
  fft256_r4(lds[wave], W256s, lane);
  // z[n] = conj(R[n])/256 ; y[2n]=Re, y[2n+1]=Im ; hann from table; stage LDS
#pragma unroll
  for (int j = 0; j < 4; j++) {
    int n = lane + 64 * j;
    float2 r = lds[wave][0][SWZ(n)];
    float y0 = r.x * (1.0f / 256.0f);
    float y1 = -r.y * (1.0f / 256.0f);
    int t0 = 2 * n, t1 = 2 * n + 1;
    float h0 = 0.5f - 0.5f * W512s[(t0 <= 256) ? t0 : (512 - t0)].x;
    float h1 = 0.5f - 0.5f * W512s[(t1 <= 256) ? t1 : (512 - t1)].x;
    u.w2[wave][n] = make_float2(y0 * h0, y1 * h1);
  }
  __syncthreads();
  const float* wout = (const float*)u.w2;   // [FPB][512] view
  float g = gain[bc & (NCH - 1)];
  // interior chunks m=1..3: frame(m-1) tail + frame(m) head -> tanh -> out
  size_t obase = (size_t)bc * T_LEN + (size_t)blk * (FPB * HOP);
#pragma unroll
  for (int it = 0; it < 3; it++) {
    int idx = it * 256 + threadIdx.x;       // 0..767
    int m = (idx >> 8) + 1, s = idx & 255;
    float v = wout[(m - 1) * WIN + HOP + s] + wout[m * WIN + s];
    out[obase + m * HOP + s] = tanhf(g * v);
  }
  // boundary halves -> side buffer: [bc][blk][2][HOP]
  float* bp = bnd + (((size_t)bc * NBLK + blk) * 2) * HOP;
  bp[threadIdx.x]       = wout[0 * WIN + threadIdx.x];              // leading head
  bp[HOP + threadIdx.x] = wout[(FPB - 1) * WIN + HOP + threadIdx.x]; // trailing tail
}

// ---------------------------------------------------------------------------
// 5) combine boundary chunks: chunk 4b <- bnd[b-1].tail + bnd[b].head
// ---------------------------------------------------------------------------
__global__ __launch_bounds__(256) void final_kernel(const float* __restrict__ bnd,
                                                    const float* __restrict__ gain,
                                                    float* __restrict__ out) {
  int bc = blockIdx.y, b = blockIdx.x;
  int s = threadIdx.x;
  const float* base = bnd + ((size_t)bc * NBLK) * 2 * HOP;
  float v = base[((size_t)b * 2) * HOP + s];                       // head of block b
  if (b > 0) v += base[((size_t)(b - 1) * 2 + 1) * HOP + s];       // tail of block b-1
  float g = gain[bc & (NCH - 1)];
  out[(size_t)bc * T_LEN + (size_t)b * (FPB * HOP) + s] = tanhf(g * v);
}

// ---------------------------------------------------------------------------
extern "C" void kernel_launch(void* const* d_in, const int* in_sizes, int n_in,
                              void* d_out, int out_size, void* d_ws, size_t ws_size,
                              hipStream_t stream) {
  (void)in_sizes; (void)n_in; (void)out_size; (void)ws_size;
  const float* x        = (const float*)d_in[0];
  const float* transfer = (const float*)d_in[1];
  const float* mixer    = (const float*)d_in[2];
  const float* gain     = (const float*)d_in[3];
  float* out = (float*)d_out;

  // workspace layout: [spec: NBC*NFR*NBIN float2 ~134.5MB][y: NBC*T floats ~67MB]
  // bnd (33.5MB) aliases y (dead after fft_fwd).
  float2* spec = (float2*)d_ws;
  size_t spec_bytes = (size_t)NBC * NFR * NBIN * sizeof(float2);
  float* y   = (float*)((char*)d_ws + spec_bytes);
  float* bnd = y;

  mix_kernel<<<dim3(T_LEN / 256, NBAT), 256, 0, stream>>>(x, mixer, y);
  fft_fwd_kernel<<<dim3(NBLK, NBC), 256, 0, stream>>>(y, spec);
  scan_kernel<<<dim3((NBC * NBIN + 255) / 256), 256, 0, stream>>>(spec, transfer);
  fft_inv_kernel<<<dim3(NBLK, NBC), 256, 0, stream>>>(spec, gain, out, bnd);
  final_kernel<<<dim3(NBLK, NBC), 256, 0, stream>>>(bnd, gain, out);
}

// Round 4
// 191.836 us; speedup vs baseline: 2.0840x; 1.0313x over previous
//
#include <hip/hip_runtime.h>
#include <math.h>

// Problem constants
#define T_LEN 131072
#define NCH   32
#define NBAT  4
#define WIN   512
#define HOP   256
#define NFR   512            // frames per (b,c) = T/HOP
#define NBIN  257            // rfft bins
#define NBC   (NBAT*NCH)     // 128
#define FPB   4              // frames per block (fwd + inv) == scan chunk
#define NBLK  (NFR/FPB)      // 128 chunks per bc
#define TWOPI 6.28318530717958647692f

// XOR swizzle for FFT LDS float2 arrays (reaches the b64 4-lane/bank floor)
#define SWZ(m) ((m) ^ ((((m) >> 4) & 15)))

__device__ __forceinline__ float2 cmul(float2 u, float2 v) {
  return make_float2(fmaf(u.x, v.x, -u.y * v.y), fmaf(u.x, v.y, u.y * v.x));
}

__device__ __forceinline__ float fast_tanh(float x) {
  float e = __expf(2.0f * x);                    // inf-safe: e=inf -> 1, e=0 -> -1
  return 1.0f - 2.0f * __builtin_amdgcn_rcpf(e + 1.0f);
}

// ---------------------------------------------------------------------------
// 1) channel mix: y[b,d,t] = sum_c x[b,c,t] * mixer[c,d]
// ---------------------------------------------------------------------------
__global__ __launch_bounds__(256) void mix_kernel(const float* __restrict__ x,
                                                  const float* __restrict__ mixer,
                                                  float* __restrict__ y) {
  __shared__ float xs[NCH][256];
  __shared__ float mm[NCH][NCH];
  int b = blockIdx.y;
  int t = blockIdx.x * 256 + threadIdx.x;
  for (int i = threadIdx.x; i < NCH * NCH; i += 256)
    ((float*)mm)[i] = mixer[i];
  for (int c = 0; c < NCH; c++)
    xs[c][threadIdx.x] = x[((size_t)(b * NCH + c)) * T_LEN + t];
  __syncthreads();
  float xr[NCH];
#pragma unroll
  for (int c = 0; c < NCH; c++) xr[c] = xs[c][threadIdx.x];
#pragma unroll 4
  for (int d = 0; d < NCH; d++) {
    float acc = 0.f;
#pragma unroll
    for (int c = 0; c < NCH; c++) acc = fmaf(xr[c], mm[c][d], acc);
    y[((size_t)(b * NCH + d)) * T_LEN + t] = acc;
  }
}

// ---------------------------------------------------------------------------
// 256-pt complex Stockham radix-4 FFT (per-wave, LDS dbuf, full twiddle table)
// ---------------------------------------------------------------------------
__device__ __forceinline__ void fft256_r4(float2 (*buf)[256],
                                          const float2* __restrict__ W256f,
                                          int lane) {
  int cur = 0;
#pragma unroll
  for (int st = 0; st < 4; st++) {
    int s = 1 << (2 * st);
    int p = lane >> (2 * st);
    int ps = p * s;                 // <= 63
    float2 a = buf[cur][SWZ(lane)];
    float2 b = buf[cur][SWZ(lane + 64)];
    float2 c = buf[cur][SWZ(lane + 128)];
    float2 d = buf[cur][SWZ(lane + 192)];
    float2 w1 = W256f[ps];
    float2 w2 = W256f[2 * ps];
    float2 w3 = W256f[3 * ps];
    float2 apc = make_float2(a.x + c.x, a.y + c.y);
    float2 amc = make_float2(a.x - c.x, a.y - c.y);
    float2 bpd = make_float2(b.x + d.x, b.y + d.y);
    float2 bmd = make_float2(b.x - d.x, b.y - d.y);
    float2 y0 = make_float2(apc.x + bpd.x, apc.y + bpd.y);
    float2 t1 = make_float2(amc.x + bmd.y, amc.y - bmd.x);  // amc - i*bmd
    float2 t2 = make_float2(apc.x - bpd.x, apc.y - bpd.y);
    float2 t3 = make_float2(amc.x - bmd.y, amc.y + bmd.x);  // amc + i*bmd
    int o = lane + 3 * ps;
    buf[cur ^ 1][SWZ(o)]         = y0;
    buf[cur ^ 1][SWZ(o + s)]     = cmul(w1, t1);
    buf[cur ^ 1][SWZ(o + 2 * s)] = cmul(w2, t2);
    buf[cur ^ 1][SWZ(o + 3 * s)] = cmul(w3, t3);
    cur ^= 1;
    __syncthreads();
  }
}

// W256f[m] = exp(-2pi i m/256), m<256 ; W512s[k] = exp(-2pi i k/512), k<=256
__device__ __forceinline__ void build_tables(float2* W256f, float2* W512s) {
  int tid = threadIdx.x;
  float sv, cv;
  __sincosf(-(TWOPI / 256.0f) * (float)tid, &sv, &cv);
  W256f[tid] = make_float2(cv, sv);
  __sincosf(-(TWOPI / 512.0f) * (float)tid, &sv, &cv);
  W512s[tid] = make_float2(cv, sv);
  if (tid == 0) W512s[256] = make_float2(-1.f, 0.f);
}

// ---------------------------------------------------------------------------
// 2) forward rfft(512) + LOCAL scan over the block's 4 frames (zero init).
//    Writes locally-scanned spectra; chunk-final state is frame 4*blk+3.
// ---------------------------------------------------------------------------
__global__ __launch_bounds__(256) void fft_fwd_kernel(const float* __restrict__ y,
                                                      const float* __restrict__ transfer,
                                                      float2* __restrict__ spec) {
  __shared__ float xin[FPB * HOP + WIN];          // 1280 floats
  __shared__ float2 lds[FPB][2][256];
  __shared__ float2 yb[FPB][NBIN];
  __shared__ float2 W256f[256];
  __shared__ float2 W512s[NBIN];
  build_tables(W256f, W512s);
  int wave = threadIdx.x >> 6, lane = threadIdx.x & 63;
  int bc = blockIdx.y, blk = blockIdx.x;
  size_t ybase = (size_t)bc * T_LEN + (size_t)blk * (FPB * HOP);
#pragma unroll
  for (int it = 0; it < 5; it++) {
    int i = it * 256 + threadIdx.x;
    int pos = blk * (FPB * HOP) + i;
    xin[i] = (pos < T_LEN) ? y[ybase + i] : 0.f;
  }
  __syncthreads();
  // pack z[n] = y[2n] + i*y[2n+1]
#pragma unroll
  for (int j = 0; j < 4; j++) {
    int n = lane + 64 * j;
    lds[wave][0][SWZ(n)] = make_float2(xin[wave * HOP + 2 * n],
                                       xin[wave * HOP + 2 * n + 1]);
  }
  __syncthreads();
  fft256_r4(lds[wave], W256f, lane);
  // untangle: Y[k] = E[k] + W^k O[k] -> yb[wave][k]
  const float2* Z = lds[wave][0];
#pragma unroll
  for (int j = 0; j < 5; j++) {
    int k = lane + 64 * j;
    if (k <= 256) {
      float2 zk  = Z[SWZ(k & 255)];
      float2 zmk = Z[SWZ((256 - k) & 255)];
      float Ex = 0.5f * (zk.x + zmk.x), Ey = 0.5f * (zk.y - zmk.y);
      float dx = 0.5f * (zk.x - zmk.x), dy = 0.5f * (zk.y + zmk.y);
      float Ox = dy, Oy = -dx;   // O = -i*(dx + i*dy)
      float cw = W512s[k].x, sw = W512s[k].y;
      yb[wave][k] = make_float2(Ex + Ox * cw - Oy * sw,
                                Ey + Ox * sw + Oy * cw);
    }
  }
  __syncthreads();
  // local scan over the 4 frames (thread per bin)
  int ch = bc & (NCH - 1);
  for (int k = threadIdx.x; k < NBIN; k += 256) {
    float tr = transfer[ch * NBIN + k];
    float sx = 0.f, sy = 0.f;
#pragma unroll
    for (int f = 0; f < FPB; f++) {
      float2 v = yb[f][k];
      sx = tr * (v.x + sx);
      sy = tr * (v.y + sy);
      yb[f][k] = make_float2(sx, sy);
    }
  }
  __syncthreads();
  // write locally-scanned spectra
  size_t fbase = ((size_t)bc * NFR + (size_t)blk * FPB + wave) * NBIN;
#pragma unroll
  for (int j = 0; j < 5; j++) {
    int k = lane + 64 * j;
    if (k <= 256) spec[fbase + k] = yb[wave][k];
  }
}

// ---------------------------------------------------------------------------
// 3) carry scan across chunks: C[0]=0; C[i] = final[i-1] + tr^FPB * C[i-1]
//    final[i] = spec[bc][FPB*i + FPB-1][k] (locally-scanned last frame)
// ---------------------------------------------------------------------------
__global__ __launch_bounds__(256) void carry_kernel(const float2* __restrict__ spec,
                                                    const float* __restrict__ transfer,
                                                    float2* __restrict__ carries) {
  int tid = blockIdx.x * 256 + threadIdx.x;
  if (tid >= NBC * NBIN) return;
  int bc = tid / NBIN, k = tid - bc * NBIN;
  int ch = bc & (NCH - 1);
  float tr = transfer[ch * NBIN + k];
  float tr2 = tr * tr;
  float tr4 = tr2 * tr2;          // tr^FPB
  const float2* fin = spec + (size_t)bc * NFR * NBIN + (size_t)(FPB - 1) * NBIN + k;
  float2* cp = carries + (size_t)bc * NBLK * NBIN + k;
  float cx = 0.f, cy = 0.f;
  for (int i = 0; i < NBLK; i += 8) {
    float2 v[8];
#pragma unroll
    for (int u = 0; u < 8; u++) v[u] = fin[(size_t)(i + u) * FPB * NBIN];
#pragma unroll
    for (int u = 0; u < 8; u++) {
      cp[(size_t)(i + u) * NBIN] = make_float2(cx, cy);
      cx = v[u].x + tr4 * cx;
      cy = v[u].y + tr4 * cy;
    }
  }
}

// ---------------------------------------------------------------------------
// 4) inverse rfft + hann + block-local OLA. Applies carry fix-up on load:
//    O[f] = local[f] + tr^(wave+1) * carry[chunk]
// ---------------------------------------------------------------------------
__global__ __launch_bounds__(256) void fft_inv_kernel(const float2* __restrict__ spec,
                                                      const float2* __restrict__ carries,
                                                      const float* __restrict__ transfer,
                                                      const float* __restrict__ gain,
                                                      float* __restrict__ out,
                                                      float* __restrict__ bnd) {
  __shared__ float2 lds[FPB][2][256];
  __shared__ union {
    float2 yb[FPB][NBIN];
    float2 w2[FPB][256];
  } u;
  __shared__ float2 W256f[256];
  __shared__ float2 W512s[NBIN];
  build_tables(W256f, W512s);
  int wave = threadIdx.x >> 6, lane = threadIdx.x & 63;
  int bc = blockIdx.y, blk = blockIdx.x;
  int ch = bc & (NCH - 1);
  const float2* sp = spec + ((size_t)bc * NFR + (size_t)blk * FPB + wave) * NBIN;
  const float2* cr = carries + ((size_t)bc * NBLK + blk) * NBIN;
#pragma unroll
  for (int j = 0; j < 5; j++) {
    int k = lane + 64 * j;
    if (k <= 256) {
      float2 loc = sp[k];
      float2 cv  = cr[k];
      float tr = transfer[ch * NBIN + k];
      float trp = tr;                       // tr^(wave+1), wave-uniform loop
#pragma unroll
      for (int w = 0; w < FPB - 1; w++) if (wave > w) trp *= tr;
      u.yb[wave][k] = make_float2(loc.x + trp * cv.x, loc.y + trp * cv.y);
    }
  }
  __syncthreads();
  // inverse untangle: Z[k] = E[k] + i*O[k]; store conj(Z) for ifft-via-fft
#pragma unroll
  for (int j = 0; j < 4; j++) {
    int k = lane + 64 * j;          // 0..255
    float2 yk  = u.yb[wave][k];
    float2 ymk = u.yb[wave][256 - k];
    float Ex = 0.5f * (yk.x + ymk.x), Ey = 0.5f * (yk.y - ymk.y);
    float dx = 0.5f * (yk.x - ymk.x), dy = 0.5f * (yk.y + ymk.y);
    float cw = W512s[k].x, sw = -W512s[k].y;   // exp(+2pi i k/512)
    float Ox = dx * cw - dy * sw, Oy = dx * sw + dy * cw;
    lds[wave][0][SWZ(k)] = make_float2(Ex - Oy, -(Ey + Ox));
  }
  __syncthreads();
  fft256_r4(lds[wave], W256f, lane);
  // z[n] = conj(R[n])/256 ; hann from table; stage windowed frame in LDS
#pragma unroll
  for (int j = 0; j < 4; j++) {
    int n = lane + 64 * j;
    float2 r = lds[wave][0][SWZ(n)];
    float y0 = r.x * (1.0f / 256.0f);
    float y1 = -r.y * (1.0f / 256.0f);
    int t0 = 2 * n, t1 = 2 * n + 1;
    float h0 = 0.5f - 0.5f * W512s[(t0 <= 256) ? t0 : (512 - t0)].x;
    float h1 = 0.5f - 0.5f * W512s[(t1 <= 256) ? t1 : (512 - t1)].x;
    u.w2[wave][n] = make_float2(y0 * h0, y1 * h1);
  }
  __syncthreads();
  const float* wout = (const float*)u.w2;   // [FPB][512] view
  float g = gain[ch];
  size_t obase = (size_t)bc * T_LEN + (size_t)blk * (FPB * HOP);
#pragma unroll
  for (int it = 0; it < 3; it++) {
    int idx = it * 256 + threadIdx.x;       // 0..767
    int m = (idx >> 8) + 1, s = idx & 255;
    float v = wout[(m - 1) * WIN + HOP + s] + wout[m * WIN + s];
    out[obase + m * HOP + s] = fast_tanh(g * v);
  }
  // boundary halves -> side buffer: [bc][blk][2][HOP]
  float* bp = bnd + (((size_t)bc * NBLK + blk) * 2) * HOP;
  bp[threadIdx.x]       = wout[0 * WIN + threadIdx.x];               // leading head
  bp[HOP + threadIdx.x] = wout[(FPB - 1) * WIN + HOP + threadIdx.x]; // trailing tail
}

// ---------------------------------------------------------------------------
// 5) combine boundary chunks: chunk FPB*b <- bnd[b-1].tail + bnd[b].head
// ---------------------------------------------------------------------------
__global__ __launch_bounds__(256) void final_kernel(const float* __restrict__ bnd,
                                                    const float* __restrict__ gain,
                                                    float* __restrict__ out) {
  int bc = blockIdx.y, b = blockIdx.x;
  int s = threadIdx.x;
  const float* base = bnd + ((size_t)bc * NBLK) * 2 * HOP;
  float v = base[((size_t)b * 2) * HOP + s];
  if (b > 0) v += base[((size_t)(b - 1) * 2 + 1) * HOP + s];
  float g = gain[bc & (NCH - 1)];
  out[(size_t)bc * T_LEN + (size_t)b * (FPB * HOP) + s] = fast_tanh(g * v);
}

// ---------------------------------------------------------------------------
extern "C" void kernel_launch(void* const* d_in, const int* in_sizes, int n_in,
                              void* d_out, int out_size, void* d_ws, size_t ws_size,
                              hipStream_t stream) {
  (void)in_sizes; (void)n_in; (void)out_size; (void)ws_size;
  const float* x        = (const float*)d_in[0];
  const float* transfer = (const float*)d_in[1];
  const float* mixer    = (const float*)d_in[2];
  const float* gain     = (const float*)d_in[3];
  float* out = (float*)d_out;

  // ws layout: [spec 134,742,016 B][bnd 33,554,432 B][carries 33,685,504 B]
  // y (mixed signal, 67 MB) aliases bnd+carries (dead after fft_fwd).
  float2* spec = (float2*)d_ws;
  size_t spec_bytes = (size_t)NBC * NFR * NBIN * sizeof(float2);
  float*  y       = (float*)((char*)d_ws + spec_bytes);
  float*  bnd     = y;
  size_t bnd_bytes = (size_t)NBC * NBLK * 2 * HOP * sizeof(float);
  float2* carries = (float2*)((char*)d_ws + spec_bytes + bnd_bytes);

  mix_kernel<<<dim3(T_LEN / 256, NBAT), 256, 0, stream>>>(x, mixer, y);
  fft_fwd_kernel<<<dim3(NBLK, NBC), 256, 0, stream>>>(y, transfer, spec);
  carry_kernel<<<dim3((NBC * NBIN + 255) / 256), 256, 0, stream>>>(spec, transfer, carries);
  fft_inv_kernel<<<dim3(NBLK, NBC), 256, 0, stream>>>(spec, carries, transfer, gain, out, bnd);
  final_kernel<<<dim3(NBLK, NBC), 256, 0, stream>>>(bnd, gain, out);
}

// Round 5
// 185.931 us; speedup vs baseline: 2.1502x; 1.0318x over previous
//
#include <hip/hip_runtime.h>
#include <math.h>

// Problem constants
#define T_LEN 131072
#define NCH   32
#define NBAT  4
#define WIN   512
#define HOP   256
#define NFR   512            // frames per (b,c) = T/HOP
#define NBIN  257            // rfft bins
#define NBC   (NBAT*NCH)     // 128
#define FPB   4              // frames per block (fwd + inv) == scan chunk
#define NBLK  (NFR/FPB)      // 128 chunks per bc
#define TWOPI 6.28318530717958647692f

// XOR swizzle for FFT LDS float2 arrays (reaches the b64 4-lane/bank floor)
#define SWZ(m) ((m) ^ ((((m) >> 4) & 15)))

__device__ __forceinline__ float2 cmul(float2 u, float2 v) {
  return make_float2(fmaf(u.x, v.x, -u.y * v.y), fmaf(u.x, v.y, u.y * v.x));
}

__device__ __forceinline__ float fast_tanh(float x) {
  float e = __expf(2.0f * x);                    // inf-safe: e=inf -> 1, e=0 -> -1
  return 1.0f - 2.0f * __builtin_amdgcn_rcpf(e + 1.0f);
}

// Wave-level sync: all FFT LDS buffers are wave-private. The DS pipe executes
// one wave's LDS ops in order, so intra-wave RAW through LDS needs only a
// compiler fence (no s_barrier, no vmcnt/lgkmcnt drain).
__device__ __forceinline__ void wave_sync() {
  asm volatile("" ::: "memory");
  __builtin_amdgcn_wave_barrier();
  asm volatile("" ::: "memory");
}

// ---------------------------------------------------------------------------
// 1) channel mix: y[b,d,t] = sum_c x[b,c,t] * mixer[c,d]
// ---------------------------------------------------------------------------
__global__ __launch_bounds__(256) void mix_kernel(const float* __restrict__ x,
                                                  const float* __restrict__ mixer,
                                                  float* __restrict__ y) {
  __shared__ float xs[NCH][256];
  __shared__ float mm[NCH][NCH];
  int b = blockIdx.y;
  int t = blockIdx.x * 256 + threadIdx.x;
  for (int i = threadIdx.x; i < NCH * NCH; i += 256)
    ((float*)mm)[i] = mixer[i];
  for (int c = 0; c < NCH; c++)
    xs[c][threadIdx.x] = x[((size_t)(b * NCH + c)) * T_LEN + t];
  __syncthreads();
  float xr[NCH];
#pragma unroll
  for (int c = 0; c < NCH; c++) xr[c] = xs[c][threadIdx.x];
#pragma unroll 4
  for (int d = 0; d < NCH; d++) {
    float acc = 0.f;
#pragma unroll
    for (int c = 0; c < NCH; c++) acc = fmaf(xr[c], mm[c][d], acc);
    y[((size_t)(b * NCH + d)) * T_LEN + t] = acc;
  }
}

// ---------------------------------------------------------------------------
// 256-pt complex Stockham radix-4 FFT (per-wave, LDS dbuf, table twiddles,
// wave-local sync only)
// ---------------------------------------------------------------------------
__device__ __forceinline__ void fft256_r4(float2 (*buf)[256],
                                          const float2* __restrict__ W256f,
                                          int lane) {
  int cur = 0;
#pragma unroll
  for (int st = 0; st < 4; st++) {
    int s = 1 << (2 * st);
    int p = lane >> (2 * st);
    int ps = p * s;                 // <= 63
    float2 a = buf[cur][SWZ(lane)];
    float2 b = buf[cur][SWZ(lane + 64)];
    float2 c = buf[cur][SWZ(lane + 128)];
    float2 d = buf[cur][SWZ(lane + 192)];
    float2 w1 = W256f[ps];
    float2 w2 = W256f[2 * ps];
    float2 w3 = W256f[3 * ps];
    float2 apc = make_float2(a.x + c.x, a.y + c.y);
    float2 amc = make_float2(a.x - c.x, a.y - c.y);
    float2 bpd = make_float2(b.x + d.x, b.y + d.y);
    float2 bmd = make_float2(b.x - d.x, b.y - d.y);
    float2 y0 = make_float2(apc.x + bpd.x, apc.y + bpd.y);
    float2 t1 = make_float2(amc.x + bmd.y, amc.y - bmd.x);  // amc - i*bmd
    float2 t2 = make_float2(apc.x - bpd.x, apc.y - bpd.y);
    float2 t3 = make_float2(amc.x - bmd.y, amc.y + bmd.x);  // amc + i*bmd
    int o = lane + 3 * ps;
    buf[cur ^ 1][SWZ(o)]         = y0;
    buf[cur ^ 1][SWZ(o + s)]     = cmul(w1, t1);
    buf[cur ^ 1][SWZ(o + 2 * s)] = cmul(w2, t2);
    buf[cur ^ 1][SWZ(o + 3 * s)] = cmul(w3, t3);
    cur ^= 1;
    wave_sync();
  }
}

// W256f[m] = exp(-2pi i m/256), m<256 ; W512s[k] = exp(-2pi i k/512), k<=256
__device__ __forceinline__ void build_tables(float2* W256f, float2* W512s) {
  int tid = threadIdx.x;
  float sv, cv;
  __sincosf(-(TWOPI / 256.0f) * (float)tid, &sv, &cv);
  W256f[tid] = make_float2(cv, sv);
  __sincosf(-(TWOPI / 512.0f) * (float)tid, &sv, &cv);
  W512s[tid] = make_float2(cv, sv);
  if (tid == 0) W512s[256] = make_float2(-1.f, 0.f);
}

// ---------------------------------------------------------------------------
// 2) forward rfft(512) + LOCAL scan over the block's 4 frames (zero init).
// ---------------------------------------------------------------------------
__global__ __launch_bounds__(256) void fft_fwd_kernel(const float* __restrict__ y,
                                                      const float* __restrict__ transfer,
                                                      float2* __restrict__ spec) {
  __shared__ float xin[FPB * HOP + WIN];          // 1280 floats
  __shared__ float2 lds[FPB][2][256];
  __shared__ float2 yb[FPB][NBIN];
  __shared__ float2 W256f[256];
  __shared__ float2 W512s[NBIN];
  build_tables(W256f, W512s);
  int wave = threadIdx.x >> 6, lane = threadIdx.x & 63;
  int bc = blockIdx.y, blk = blockIdx.x;
  size_t ybase = (size_t)bc * T_LEN + (size_t)blk * (FPB * HOP);
#pragma unroll
  for (int it = 0; it < 5; it++) {
    int i = it * 256 + threadIdx.x;
    int pos = blk * (FPB * HOP) + i;
    xin[i] = (pos < T_LEN) ? y[ybase + i] : 0.f;
  }
  __syncthreads();                 // xin + twiddle tables visible block-wide
  // pack z[n] = y[2n] + i*y[2n+1] (into this wave's private buffer)
#pragma unroll
  for (int j = 0; j < 4; j++) {
    int n = lane + 64 * j;
    lds[wave][0][SWZ(n)] = make_float2(xin[wave * HOP + 2 * n],
                                       xin[wave * HOP + 2 * n + 1]);
  }
  wave_sync();
  fft256_r4(lds[wave], W256f, lane);
  // untangle: Y[k] = E[k] + W^k O[k] -> yb[wave][k]  (wave-private)
  const float2* Z = lds[wave][0];
#pragma unroll
  for (int j = 0; j < 5; j++) {
    int k = lane + 64 * j;
    if (k <= 256) {
      float2 zk  = Z[SWZ(k & 255)];
      float2 zmk = Z[SWZ((256 - k) & 255)];
      float Ex = 0.5f * (zk.x + zmk.x), Ey = 0.5f * (zk.y - zmk.y);
      float dx = 0.5f * (zk.x - zmk.x), dy = 0.5f * (zk.y + zmk.y);
      float Ox = dy, Oy = -dx;   // O = -i*(dx + i*dy)
      float cw = W512s[k].x, sw = W512s[k].y;
      yb[wave][k] = make_float2(Ex + Ox * cw - Oy * sw,
                                Ey + Ox * sw + Oy * cw);
    }
  }
  __syncthreads();                 // yb crosses waves for the scan
  // local scan over the 4 frames (thread per bin)
  int ch = bc & (NCH - 1);
  for (int k = threadIdx.x; k < NBIN; k += 256) {
    float tr = transfer[ch * NBIN + k];
    float sx = 0.f, sy = 0.f;
#pragma unroll
    for (int f = 0; f < FPB; f++) {
      float2 v = yb[f][k];
      sx = tr * (v.x + sx);
      sy = tr * (v.y + sy);
      yb[f][k] = make_float2(sx, sy);
    }
  }
  __syncthreads();                 // scanned yb visible to all
  // write locally-scanned spectra
  size_t fbase = ((size_t)bc * NFR + (size_t)blk * FPB + wave) * NBIN;
#pragma unroll
  for (int j = 0; j < 5; j++) {
    int k = lane + 64 * j;
    if (k <= 256) spec[fbase + k] = yb[wave][k];
  }
}

// ---------------------------------------------------------------------------
// 3) carry scan across chunks: C[0]=0; C[i] = final[i-1] + tr^FPB * C[i-1]
// ---------------------------------------------------------------------------
__global__ __launch_bounds__(256) void carry_kernel(const float2* __restrict__ spec,
                                                    const float* __restrict__ transfer,
                                                    float2* __restrict__ carries) {
  int tid = blockIdx.x * 256 + threadIdx.x;
  if (tid >= NBC * NBIN) return;
  int bc = tid / NBIN, k = tid - bc * NBIN;
  int ch = bc & (NCH - 1);
  float tr = transfer[ch * NBIN + k];
  float tr2 = tr * tr;
  float tr4 = tr2 * tr2;          // tr^FPB
  const float2* fin = spec + (size_t)bc * NFR * NBIN + (size_t)(FPB - 1) * NBIN + k;
  float2* cp = carries + (size_t)bc * NBLK * NBIN + k;
  float cx = 0.f, cy = 0.f;
  for (int i = 0; i < NBLK; i += 8) {
    float2 v[8];
#pragma unroll
    for (int u = 0; u < 8; u++) v[u] = fin[(size_t)(i + u) * FPB * NBIN];
#pragma unroll
    for (int u = 0; u < 8; u++) {
      cp[(size_t)(i + u) * NBIN] = make_float2(cx, cy);
      cx = v[u].x + tr4 * cx;
      cy = v[u].y + tr4 * cy;
    }
  }
}

// ---------------------------------------------------------------------------
// 4) inverse rfft + hann + block-local OLA with carry fix-up on load.
//    u.w2 re-laid-out with the SAME [FPB][NBIN] stride as u.yb so the
//    yb->w2 aliasing stays wave-private (no cross-wave hazard).
// ---------------------------------------------------------------------------
__global__ __launch_bounds__(256) void fft_inv_kernel(const float2* __restrict__ spec,
                                                      const float2* __restrict__ carries,
                                                      const float* __restrict__ transfer,
                                                      const float* __restrict__ gain,
                                                      float* __restrict__ out,
                                                      float* __restrict__ bnd) {
  __shared__ float2 lds[FPB][2][256];
  __shared__ union {
    float2 yb[FPB][NBIN];
    float2 w2[FPB][NBIN];     // only [0..255] used per frame; same stride
  } u;
  __shared__ float2 W256f[256];
  __shared__ float2 W512s[NBIN];
  build_tables(W256f, W512s);
  int wave = threadIdx.x >> 6, lane = threadIdx.x & 63;
  int bc = blockIdx.y, blk = blockIdx.x;
  int ch = bc & (NCH - 1);
  const float2* sp = spec + ((size_t)bc * NFR + (size_t)blk * FPB + wave) * NBIN;
  const float2* cr = carries + ((size_t)bc * NBLK + blk) * NBIN;
#pragma unroll
  for (int j = 0; j < 5; j++) {
    int k = lane + 64 * j;
    if (k <= 256) {
      float2 loc = sp[k];
      float2 cv  = cr[k];
      float tr = transfer[ch * NBIN + k];
      float trp = tr;                       // tr^(wave+1), wave-uniform loop
#pragma unroll
      for (int w = 0; w < FPB - 1; w++) if (wave > w) trp *= tr;
      u.yb[wave][k] = make_float2(loc.x + trp * cv.x, loc.y + trp * cv.y);
    }
  }
  __syncthreads();                 // twiddle tables visible (yb is wave-local)
  // inverse untangle: Z[k] = E[k] + i*O[k]; store conj(Z) for ifft-via-fft
#pragma unroll
  for (int j = 0; j < 4; j++) {
    int k = lane + 64 * j;          // 0..255
    float2 yk  = u.yb[wave][k];
    float2 ymk = u.yb[wave][256 - k];
    float Ex = 0.5f * (yk.x + ymk.x), Ey = 0.5f * (yk.y - ymk.y);
    float dx = 0.5f * (yk.x - ymk.x), dy = 0.5f * (yk.y + ymk.y);
    float cw = W512s[k].x, sw = -W512s[k].y;   // exp(+2pi i k/512)
    float Ox = dx * cw - dy * sw, Oy = dx * sw + dy * cw;
    lds[wave][0][SWZ(k)] = make_float2(Ex - Oy, -(Ey + Ox));
  }
  wave_sync();
  fft256_r4(lds[wave], W256f, lane);
  // z[n] = conj(R[n])/256 ; hann from table; stage windowed frame (wave-local)
#pragma unroll
  for (int j = 0; j < 4; j++) {
    int n = lane + 64 * j;
    float2 r = lds[wave][0][SWZ(n)];
    float y0 = r.x * (1.0f / 256.0f);
    float y1 = -r.y * (1.0f / 256.0f);
    int t0 = 2 * n, t1 = 2 * n + 1;
    float h0 = 0.5f - 0.5f * W512s[(t0 <= 256) ? t0 : (512 - t0)].x;
    float h1 = 0.5f - 0.5f * W512s[(t1 <= 256) ? t1 : (512 - t1)].x;
    u.w2[wave][n] = make_float2(y0 * h0, y1 * h1);
  }
  __syncthreads();                 // windowed frames cross waves for OLA
  const float* wout = (const float*)u.w2;   // frame m at stride 2*NBIN floats
  float g = gain[ch];
  size_t obase = (size_t)bc * T_LEN + (size_t)blk * (FPB * HOP);
#pragma unroll
  for (int it = 0; it < 3; it++) {
    int idx = it * 256 + threadIdx.x;       // 0..767
    int m = (idx >> 8) + 1, s = idx & 255;
    float v = wout[(m - 1) * (2 * NBIN) + HOP + s] + wout[m * (2 * NBIN) + s];
    out[obase + m * HOP + s] = fast_tanh(g * v);
  }
  // boundary halves -> side buffer: [bc][blk][2][HOP]
  float* bp = bnd + (((size_t)bc * NBLK + blk) * 2) * HOP;
  bp[threadIdx.x]       = wout[threadIdx.x];                             // head
  bp[HOP + threadIdx.x] = wout[(FPB - 1) * (2 * NBIN) + HOP + threadIdx.x]; // tail
}

// ---------------------------------------------------------------------------
// 5) combine boundary chunks: chunk FPB*b <- bnd[b-1].tail + bnd[b].head
// ---------------------------------------------------------------------------
__global__ __launch_bounds__(256) void final_kernel(const float* __restrict__ bnd,
                                                    const float* __restrict__ gain,
                                                    float* __restrict__ out) {
  int bc = blockIdx.y, b = blockIdx.x;
  int s = threadIdx.x;
  const float* base = bnd + ((size_t)bc * NBLK) * 2 * HOP;
  float v = base[((size_t)b * 2) * HOP + s];
  if (b > 0) v += base[((size_t)(b - 1) * 2 + 1) * HOP + s];
  float g = gain[bc & (NCH - 1)];
  out[(size_t)bc * T_LEN + (size_t)b * (FPB * HOP) + s] = fast_tanh(g * v);
}

// ---------------------------------------------------------------------------
extern "C" void kernel_launch(void* const* d_in, const int* in_sizes, int n_in,
                              void* d_out, int out_size, void* d_ws, size_t ws_size,
                              hipStream_t stream) {
  (void)in_sizes; (void)n_in; (void)out_size; (void)ws_size;
  const float* x        = (const float*)d_in[0];
  const float* transfer = (const float*)d_in[1];
  const float* mixer    = (const float*)d_in[2];
  const float* gain     = (const float*)d_in[3];
  float* out = (float*)d_out;

  // ws layout: [spec 134,742,016 B][bnd 33,554,432 B][carries 33,685,504 B]
  // y (mixed signal, 67 MB) aliases bnd+carries (dead after fft_fwd).
  float2* spec = (float2*)d_ws;
  size_t spec_bytes = (size_t)NBC * NFR * NBIN * sizeof(float2);
  float*  y       = (float*)((char*)d_ws + spec_bytes);
  float*  bnd     = y;
  size_t bnd_bytes = (size_t)NBC * NBLK * 2 * HOP * sizeof(float);
  float2* carries = (float2*)((char*)d_ws + spec_bytes + bnd_bytes);

  mix_kernel<<<dim3(T_LEN / 256, NBAT), 256, 0, stream>>>(x, mixer, y);
  fft_fwd_kernel<<<dim3(NBLK, NBC), 256, 0, stream>>>(y, transfer, spec);
  carry_kernel<<<dim3((NBC * NBIN + 255) / 256), 256, 0, stream>>>(spec, transfer, carries);
  fft_inv_kernel<<<dim3(NBLK, NBC), 256, 0, stream>>>(spec, carries, transfer, gain, out, bnd);
  final_kernel<<<dim3(NBLK, NBC), 256, 0, stream>>>(bnd, gain, out);
}

// Round 6
// 152.795 us; speedup vs baseline: 2.6165x; 1.2169x over previous
//
#include <hip/hip_runtime.h>
#include <math.h>

// Problem constants
#define T_LEN 131072
#define NCH   32
#define NBAT  4
#define WIN   512
#define HOP   256
#define NFR   512            // frames per (b,c) = T/HOP
#define NBIN  257            // rfft bins
#define NBC   (NBAT*NCH)     // 128
#define FPB   4              // frames per chunk (one wave per chunk)
#define NBLK  (NFR/FPB)      // 128 chunks per bc
#define TWOPI 6.28318530717958647692f

// XOR swizzle for FFT LDS float2 arrays (hits the b64 4-lane/bank floor)
#define SWZ(m) ((m) ^ ((((m) >> 4) & 15)))

__device__ __forceinline__ float2 cmul(float2 u, float2 v) {
  return make_float2(fmaf(u.x, v.x, -u.y * v.y), fmaf(u.x, v.y, u.y * v.x));
}

__device__ __forceinline__ float fast_tanh(float x) {
  float e = __expf(2.0f * x);                    // inf-safe
  return 1.0f - 2.0f * __builtin_amdgcn_rcpf(e + 1.0f);
}

// Wave-level ordering fence: LDS ops of a wave execute in order on the DS
// pipe; this only stops compiler reordering (no s_barrier, no cnt drain).
__device__ __forceinline__ void wave_sync() {
  asm volatile("" ::: "memory");
  __builtin_amdgcn_wave_barrier();
  asm volatile("" ::: "memory");
}

// radix-4 DIF butterfly
__device__ __forceinline__ void r4bf(float2 a, float2 b, float2 c, float2 d,
                                     float2& y0, float2& t1, float2& t2, float2& t3) {
  float2 apc = make_float2(a.x + c.x, a.y + c.y);
  float2 amc = make_float2(a.x - c.x, a.y - c.y);
  float2 bpd = make_float2(b.x + d.x, b.y + d.y);
  float2 bmd = make_float2(b.x - d.x, b.y - d.y);
  y0 = make_float2(apc.x + bpd.x, apc.y + bpd.y);
  t1 = make_float2(amc.x + bmd.y, amc.y - bmd.x);  // amc - i*bmd
  t2 = make_float2(apc.x - bpd.x, apc.y - bpd.y);
  t3 = make_float2(amc.x - bmd.y, amc.y + bmd.x);  // amc + i*bmd
}

struct TW {
  float2 a1, a2, a3, b1, b2, b3, c1, c2, c3;
};

__device__ __forceinline__ void load_tw(const float2* __restrict__ W256f, int lane, TW& t) {
  t.a1 = W256f[lane];     t.a2 = W256f[2 * lane];  t.a3 = W256f[3 * lane];
  int p1 = 4 * (lane >> 2);
  t.b1 = W256f[p1];       t.b2 = W256f[2 * p1];    t.b3 = W256f[3 * p1];
  int p2 = 16 * (lane >> 4);
  t.c1 = W256f[p2];       t.c2 = W256f[2 * p2];    t.c3 = W256f[3 * p2];
}

// 256-pt forward complex FFT. Input regs z0..z3 = z[lane+64m]; output regs
// z0..z3 = Z[lane+64m]. Stages 0 & 3 in registers; 1 & 2 via wave-private LDS.
__device__ __forceinline__ void fft256_reg(float2& z0, float2& z1, float2& z2, float2& z3,
                                           float2* __restrict__ buf, int lane, const TW& tw) {
  float2 y0, t1, t2, t3;
  // stage 0 (s=1, p=lane): pure register butterfly, scatter 4l..4l+3
  r4bf(z0, z1, z2, z3, y0, t1, t2, t3);
  int o0 = 4 * lane;
  buf[SWZ(o0)]     = y0;
  buf[SWZ(o0 + 1)] = cmul(tw.a1, t1);
  buf[SWZ(o0 + 2)] = cmul(tw.a2, t2);
  buf[SWZ(o0 + 3)] = cmul(tw.a3, t3);
  wave_sync();
  // stage 1 (s=4)
  {
    float2 a = buf[SWZ(lane)], b = buf[SWZ(lane + 64)],
           c = buf[SWZ(lane + 128)], d = buf[SWZ(lane + 192)];
    wave_sync();
    r4bf(a, b, c, d, y0, t1, t2, t3);
    int o = lane + 12 * (lane >> 2);
    buf[SWZ(o)]      = y0;
    buf[SWZ(o + 4)]  = cmul(tw.b1, t1);
    buf[SWZ(o + 8)]  = cmul(tw.b2, t2);
    buf[SWZ(o + 12)] = cmul(tw.b3, t3);
  }
  wave_sync();
  // stage 2 (s=16)
  {
    float2 a = buf[SWZ(lane)], b = buf[SWZ(lane + 64)],
           c = buf[SWZ(lane + 128)], d = buf[SWZ(lane + 192)];
    wave_sync();
    r4bf(a, b, c, d, y0, t1, t2, t3);
    int o = lane + 48 * (lane >> 4);
    buf[SWZ(o)]      = y0;
    buf[SWZ(o + 16)] = cmul(tw.c1, t1);
    buf[SWZ(o + 32)] = cmul(tw.c2, t2);
    buf[SWZ(o + 48)] = cmul(tw.c3, t3);
  }
  wave_sync();
  // stage 3 (s=64, p=0, twiddle-free): outputs land in register layout
  {
    float2 a = buf[SWZ(lane)], b = buf[SWZ(lane + 64)],
           c = buf[SWZ(lane + 128)], d = buf[SWZ(lane + 192)];
    wave_sync();
    r4bf(a, b, c, d, z0, z1, z2, z3);
  }
}

// W256f[m] = exp(-2pi i m/256), m<256 ; W512s[k] = exp(-2pi i k/512), k<=256
__device__ __forceinline__ void build_tables(float2* W256f, float2* W512s) {
  int tid = threadIdx.x;
  float sv, cv;
  __sincosf(-(TWOPI / 256.0f) * (float)tid, &sv, &cv);
  W256f[tid] = make_float2(cv, sv);
  __sincosf(-(TWOPI / 512.0f) * (float)tid, &sv, &cv);
  W512s[tid] = make_float2(cv, sv);
  if (tid == 0) W512s[256] = make_float2(-1.f, 0.f);
}

// ---------------------------------------------------------------------------
// 1) channel mix: y[b,d,t] = sum_c x[b,c,t] * mixer[c,d]
// ---------------------------------------------------------------------------
__global__ __launch_bounds__(256) void mix_kernel(const float* __restrict__ x,
                                                  const float* __restrict__ mixer,
                                                  float* __restrict__ y) {
  __shared__ float xs[NCH][256];
  __shared__ float mm[NCH][NCH];
  int b = blockIdx.y;
  int t = blockIdx.x * 256 + threadIdx.x;
  for (int i = threadIdx.x; i < NCH * NCH; i += 256)
    ((float*)mm)[i] = mixer[i];
  for (int c = 0; c < NCH; c++)
    xs[c][threadIdx.x] = x[((size_t)(b * NCH + c)) * T_LEN + t];
  __syncthreads();
  float xr[NCH];
#pragma unroll
  for (int c = 0; c < NCH; c++) xr[c] = xs[c][threadIdx.x];
#pragma unroll 4
  for (int d = 0; d < NCH; d++) {
    float acc = 0.f;
#pragma unroll
    for (int c = 0; c < NCH; c++) acc = fmaf(xr[c], mm[c][d], acc);
    y[((size_t)(b * NCH + d)) * T_LEN + t] = acc;
  }
}

// ---------------------------------------------------------------------------
// 2) forward rfft(512) + register-local scan. Wave = one 4-frame chunk.
// ---------------------------------------------------------------------------
__global__ __launch_bounds__(256) void fft_fwd_kernel(const float* __restrict__ y,
                                                      const float* __restrict__ transfer,
                                                      float2* __restrict__ spec) {
  __shared__ float2 fbuf[FPB][NBIN];     // wave-private FFT/mirror buffer
  __shared__ float2 W256f[256];
  __shared__ float2 W512s[NBIN];
  build_tables(W256f, W512s);
  __syncthreads();
  int wave = threadIdx.x >> 6, lane = threadIdx.x & 63;
  int cid = blockIdx.x * FPB + wave;     // chunk id 0..16383
  int bc = cid >> 7, blk = cid & (NBLK - 1);
  int ch = bc & (NCH - 1);
  float2* buf = fbuf[wave];
  TW tw; load_tw(W256f, lane, tw);
  // frame-invariant per-bin constants, k = lane + 64q
  float cwq[4], swq[4], trq[4];
#pragma unroll
  for (int q = 0; q < 4; q++) {
    int k = lane + 64 * q;
    cwq[q] = W512s[k].x; swq[q] = W512s[k].y;
    trq[q] = transfer[ch * NBIN + k];
  }
  float tr256 = transfer[ch * NBIN + 256];
  float2 s[4] = {make_float2(0,0), make_float2(0,0), make_float2(0,0), make_float2(0,0)};
  float2 s256 = make_float2(0, 0);
  const float* src0 = y + (size_t)bc * T_LEN + (size_t)blk * (FPB * HOP);
  size_t fb = ((size_t)bc * NFR + (size_t)blk * FPB) * NBIN;
  bool lastchunk = (blk == NBLK - 1);
#pragma unroll
  for (int j = 0; j < FPB; j++) {
    const float* src = src0 + j * HOP;
    // pack: z[n] = (y[2n], y[2n+1]) for n = lane+64q — coalesced float2 loads
    float2 z0 = *(const float2*)(src + 2 * lane);
    float2 z1 = *(const float2*)(src + 2 * (lane + 64));
    float2 z2, z3;
    if (lastchunk && j == FPB - 1) {     // zero-padded final half-window
      z2 = make_float2(0, 0); z3 = make_float2(0, 0);
    } else {
      z2 = *(const float2*)(src + 2 * (lane + 128));
      z3 = *(const float2*)(src + 2 * (lane + 192));
    }
    fft256_reg(z0, z1, z2, z3, buf, lane, tw);
    // stage Z (regs) for mirror access
    buf[lane] = z0; buf[lane + 64] = z1; buf[lane + 128] = z2; buf[lane + 192] = z3;
    wave_sync();
    float2 zm0 = buf[(256 - lane) & 255];
    float2 zm1 = buf[192 - lane];
    float2 zm2 = buf[128 - lane];
    float2 zm3 = buf[64 - lane];
    float2 z0b = buf[0];
    wave_sync();
    // untangle + scan + store, k = lane + 64q
#pragma unroll
    for (int q = 0; q < 4; q++) {
      float2 zk  = (q == 0) ? z0 : (q == 1) ? z1 : (q == 2) ? z2 : z3;
      float2 zmk = (q == 0) ? zm0 : (q == 1) ? zm1 : (q == 2) ? zm2 : zm3;
      float Ex = 0.5f * (zk.x + zmk.x), Ey = 0.5f * (zk.y - zmk.y);
      float dx = 0.5f * (zk.x - zmk.x), dy = 0.5f * (zk.y + zmk.y);
      float Ox = dy, Oy = -dx;
      float Yx = Ex + Ox * cwq[q] - Oy * swq[q];
      float Yy = Ey + Ox * swq[q] + Oy * cwq[q];
      s[q].x = trq[q] * (Yx + s[q].x);
      s[q].y = trq[q] * (Yy + s[q].y);
      spec[fb + (size_t)j * NBIN + lane + 64 * q] = s[q];
    }
    // bin 256: zk = zmk = Z[0], cw=-1, sw=0 -> Y = (Z0.x - Z0.y, 0)
    s256.x = tr256 * ((z0b.x - z0b.y) + s256.x);
    s256.y = tr256 * s256.y;
    if (lane == 0) spec[fb + (size_t)j * NBIN + 256] = s256;
    wave_sync();
  }
}

// ---------------------------------------------------------------------------
// 3) carry scan across chunks: C[0]=0; C[i] = final[i-1] + tr^FPB * C[i-1]
// ---------------------------------------------------------------------------
__global__ __launch_bounds__(256) void carry_kernel(const float2* __restrict__ spec,
                                                    const float* __restrict__ transfer,
                                                    float2* __restrict__ carries) {
  int tid = blockIdx.x * 256 + threadIdx.x;
  if (tid >= NBC * NBIN) return;
  int bc = tid / NBIN, k = tid - bc * NBIN;
  int ch = bc & (NCH - 1);
  float tr = transfer[ch * NBIN + k];
  float tr2 = tr * tr;
  float tr4 = tr2 * tr2;          // tr^FPB
  const float2* fin = spec + (size_t)bc * NFR * NBIN + (size_t)(FPB - 1) * NBIN + k;
  float2* cp = carries + (size_t)bc * NBLK * NBIN + k;
  float cx = 0.f, cy = 0.f;
  for (int i = 0; i < NBLK; i += 8) {
    float2 v[8];
#pragma unroll
    for (int u = 0; u < 8; u++) v[u] = fin[(size_t)(i + u) * FPB * NBIN];
#pragma unroll
    for (int u = 0; u < 8; u++) {
      cp[(size_t)(i + u) * NBIN] = make_float2(cx, cy);
      cx = v[u].x + tr4 * cx;
      cy = v[u].y + tr4 * cy;
    }
  }
}

// ---------------------------------------------------------------------------
// 4) inverse rfft + hann + register OLA. Wave = one 4-frame chunk.
// ---------------------------------------------------------------------------
__global__ __launch_bounds__(256) void fft_inv_kernel(const float2* __restrict__ spec,
                                                      const float2* __restrict__ carries,
                                                      const float* __restrict__ transfer,
                                                      const float* __restrict__ gain,
                                                      float* __restrict__ out,
                                                      float* __restrict__ bnd) {
  __shared__ float2 fbuf[FPB][NBIN];
  __shared__ float2 W256f[256];
  __shared__ float2 W512s[NBIN];
  build_tables(W256f, W512s);
  __syncthreads();
  int wave = threadIdx.x >> 6, lane = threadIdx.x & 63;
  int cid = blockIdx.x * FPB + wave;
  int bc = cid >> 7, blk = cid & (NBLK - 1);
  int ch = bc & (NCH - 1);
  float2* buf = fbuf[wave];
  TW tw; load_tw(W256f, lane, tw);
  const float2* crp = carries + ((size_t)bc * NBLK + blk) * NBIN;
  float cwq[4], swq[4], trq[4], trp[4], h0[4], h1[4];
  float2 cv[4];
#pragma unroll
  for (int q = 0; q < 4; q++) {
    int k = lane + 64 * q;
    cwq[q] = W512s[k].x; swq[q] = -W512s[k].y;   // exp(+2pi i k/512)
    trq[q] = transfer[ch * NBIN + k];
    trp[q] = trq[q];
    cv[q] = crp[k];
    int t0 = 2 * k, t1 = 2 * k + 1;
    int i0 = (t0 <= 256) ? t0 : 512 - t0;
    int i1 = (t1 <= 256) ? t1 : 512 - t1;
    h0[q] = (0.5f - 0.5f * W512s[i0].x) * (1.0f / 256.0f);
    h1[q] = (0.5f - 0.5f * W512s[i1].x) * (1.0f / 256.0f);
  }
  float tr256 = transfer[ch * NBIN + 256], trp256 = tr256;
  float2 cv256 = crp[256];
  float g = gain[ch];
  const float2* sp0 = spec + ((size_t)bc * NFR + (size_t)blk * FPB) * NBIN;
  float2* outv = (float2*)out;
  size_t obase2 = ((size_t)bc * T_LEN + (size_t)blk * (FPB * HOP)) >> 1;
  float2* bp = (float2*)(bnd + (((size_t)bc * NBLK + blk) * 2) * HOP);
  float2 pt0, pt1;                        // previous frame's windowed tail
#pragma unroll
  for (int j = 0; j < FPB; j++) {
    const float2* sp = sp0 + (size_t)j * NBIN;
    // load + carry fix-up: O = local + tr^(j+1) * carry
    float2 Y0 = sp[lane];        Y0.x = fmaf(trp[0], cv[0].x, Y0.x); Y0.y = fmaf(trp[0], cv[0].y, Y0.y);
    float2 Y1 = sp[lane + 64];   Y1.x = fmaf(trp[1], cv[1].x, Y1.x); Y1.y = fmaf(trp[1], cv[1].y, Y1.y);
    float2 Y2 = sp[lane + 128];  Y2.x = fmaf(trp[2], cv[2].x, Y2.x); Y2.y = fmaf(trp[2], cv[2].y, Y2.y);
    float2 Y3 = sp[lane + 192];  Y3.x = fmaf(trp[3], cv[3].x, Y3.x); Y3.y = fmaf(trp[3], cv[3].y, Y3.y);
    float2 y256 = sp[256];
    y256.x = fmaf(trp256, cv256.x, y256.x);
    y256.y = fmaf(trp256, cv256.y, y256.y);
#pragma unroll
    for (int q = 0; q < 4; q++) trp[q] *= trq[q];
    trp256 *= tr256;
    // mirror staging
    buf[lane] = Y0; buf[lane + 64] = Y1; buf[lane + 128] = Y2; buf[lane + 192] = Y3;
    if (lane == 0) buf[256] = y256;
    wave_sync();
    float2 ym0 = buf[256 - lane];
    float2 ym1 = buf[192 - lane];
    float2 ym2 = buf[128 - lane];
    float2 ym3 = buf[64 - lane];
    wave_sync();
    // inverse untangle -> conj'd FFT input (register layout k = lane+64q)
    float2 z0, z1, z2, z3;
#pragma unroll
    for (int q = 0; q < 4; q++) {
      float2 yk  = (q == 0) ? Y0 : (q == 1) ? Y1 : (q == 2) ? Y2 : Y3;
      float2 ymk = (q == 0) ? ym0 : (q == 1) ? ym1 : (q == 2) ? ym2 : ym3;
      float Ex = 0.5f * (yk.x + ymk.x), Ey = 0.5f * (yk.y - ymk.y);
      float dx = 0.5f * (yk.x - ymk.x), dy = 0.5f * (yk.y + ymk.y);
      float Ox = dx * cwq[q] - dy * swq[q];
      float Oy = dx * swq[q] + dy * cwq[q];
      float2 zq = make_float2(Ex - Oy, -(Ey + Ox));
      if (q == 0) z0 = zq; else if (q == 1) z1 = zq; else if (q == 2) z2 = zq; else z3 = zq;
    }
    fft256_reg(z0, z1, z2, z3, buf, lane, tw);
    // windowed time samples: s = 2n, 2n+1 at n = lane+64q; x = conj/256
    float2 w0 = make_float2(z0.x * h0[0], -z0.y * h1[0]);
    float2 w1 = make_float2(z1.x * h0[1], -z1.y * h1[1]);
    float2 w2 = make_float2(z2.x * h0[2], -z2.y * h1[2]);
    float2 w3 = make_float2(z3.x * h0[3], -z3.y * h1[3]);
    if (j == 0) {
      bp[lane]      = w0;                 // chunk-leading head -> bnd
      bp[lane + 64] = w1;
    } else {
      float2 v0 = make_float2(pt0.x + w0.x, pt0.y + w0.y);
      float2 v1 = make_float2(pt1.x + w1.x, pt1.y + w1.y);
      outv[obase2 + (size_t)j * 128 + lane] =
          make_float2(fast_tanh(g * v0.x), fast_tanh(g * v0.y));
      outv[obase2 + (size_t)j * 128 + lane + 64] =
          make_float2(fast_tanh(g * v1.x), fast_tanh(g * v1.y));
    }
    pt0 = w2; pt1 = w3;
    wave_sync();
  }
  bp[128 + lane] = pt0;                   // chunk-trailing tail -> bnd
  bp[192 + lane] = pt1;
}

// ---------------------------------------------------------------------------
// 5) combine boundary chunks: chunk FPB*b <- bnd[b-1].tail + bnd[b].head
// ---------------------------------------------------------------------------
__global__ __launch_bounds__(256) void final_kernel(const float* __restrict__ bnd,
                                                    const float* __restrict__ gain,
                                                    float* __restrict__ out) {
  int bc = blockIdx.y, b = blockIdx.x;
  int s = threadIdx.x;
  const float* base = bnd + ((size_t)bc * NBLK) * 2 * HOP;
  float v = base[((size_t)b * 2) * HOP + s];
  if (b > 0) v += base[((size_t)(b - 1) * 2 + 1) * HOP + s];
  float g = gain[bc & (NCH - 1)];
  out[(size_t)bc * T_LEN + (size_t)b * (FPB * HOP) + s] = fast_tanh(g * v);
}

// ---------------------------------------------------------------------------
extern "C" void kernel_launch(void* const* d_in, const int* in_sizes, int n_in,
                              void* d_out, int out_size, void* d_ws, size_t ws_size,
                              hipStream_t stream) {
  (void)in_sizes; (void)n_in; (void)out_size; (void)ws_size;
  const float* x        = (const float*)d_in[0];
  const float* transfer = (const float*)d_in[1];
  const float* mixer    = (const float*)d_in[2];
  const float* gain     = (const float*)d_in[3];
  float* out = (float*)d_out;

  // ws layout: [spec 134,742,016 B][bnd 33,554,432 B][carries 33,685,504 B]
  // y (mixed signal, 67 MB) aliases bnd+carries (dead after fft_fwd).
  float2* spec = (float2*)d_ws;
  size_t spec_bytes = (size_t)NBC * NFR * NBIN * sizeof(float2);
  float*  y       = (float*)((char*)d_ws + spec_bytes);
  float*  bnd     = y;
  size_t bnd_bytes = (size_t)NBC * NBLK * 2 * HOP * sizeof(float);
  float2* carries = (float2*)((char*)d_ws + spec_bytes + bnd_bytes);

  mix_kernel<<<dim3(T_LEN / 256, NBAT), 256, 0, stream>>>(x, mixer, y);
  fft_fwd_kernel<<<dim3(NBC * NBLK / FPB), 256, 0, stream>>>(y, transfer, spec);
  carry_kernel<<<dim3((NBC * NBIN + 255) / 256), 256, 0, stream>>>(spec, transfer, carries);
  fft_inv_kernel<<<dim3(NBC * NBLK / FPB), 256, 0, stream>>>(spec, carries, transfer, gain, out, bnd);
  final_kernel<<<dim3(NBLK, NBC), 256, 0, stream>>>(bnd, gain, out);
}

// Round 7
// 121.315 us; speedup vs baseline: 3.2955x; 1.2595x over previous
//
#include <hip/hip_runtime.h>
#include <hip/hip_fp16.h>
#include <math.h>

// Problem constants
#define T_LEN 131072
#define NCH   32
#define NBAT  4
#define WIN   512
#define HOP   256
#define NFR   512            // frames per (b,c) = T/HOP
#define NBIN  257            // rfft bins
#define NBC   (NBAT*NCH)     // 128
#define FPB   4              // frames per chunk (one wave per chunk)
#define NBLK  (NFR/FPB)      // 128 chunks per bc
#define TWOPI 6.28318530717958647692f

// XOR swizzle for FFT LDS float2 arrays (hits the b64 4-lane/bank floor)
#define SWZ(m) ((m) ^ ((((m) >> 4) & 15)))

__device__ __forceinline__ float2 cmul(float2 u, float2 v) {
  return make_float2(fmaf(u.x, v.x, -u.y * v.y), fmaf(u.x, v.y, u.y * v.x));
}

__device__ __forceinline__ float fast_tanh(float x) {
  float e = __expf(2.0f * x);                    // inf-safe
  return 1.0f - 2.0f * __builtin_amdgcn_rcpf(e + 1.0f);
}

__device__ __forceinline__ float2 h2f(__half2 h) { return __half22float2(h); }
__device__ __forceinline__ __half2 f2h(float2 f) { return __float22half2_rn(f); }

// Wave-level ordering fence: LDS ops of a wave execute in order on the DS
// pipe; this only stops compiler reordering (no s_barrier, no cnt drain).
__device__ __forceinline__ void wave_sync() {
  asm volatile("" ::: "memory");
  __builtin_amdgcn_wave_barrier();
  asm volatile("" ::: "memory");
}

// radix-4 DIF butterfly
__device__ __forceinline__ void r4bf(float2 a, float2 b, float2 c, float2 d,
                                     float2& y0, float2& t1, float2& t2, float2& t3) {
  float2 apc = make_float2(a.x + c.x, a.y + c.y);
  float2 amc = make_float2(a.x - c.x, a.y - c.y);
  float2 bpd = make_float2(b.x + d.x, b.y + d.y);
  float2 bmd = make_float2(b.x - d.x, b.y - d.y);
  y0 = make_float2(apc.x + bpd.x, apc.y + bpd.y);
  t1 = make_float2(amc.x + bmd.y, amc.y - bmd.x);  // amc - i*bmd
  t2 = make_float2(apc.x - bpd.x, apc.y - bpd.y);
  t3 = make_float2(amc.x - bmd.y, amc.y + bmd.x);  // amc + i*bmd
}

struct TW {
  float2 a1, a2, a3, b1, b2, b3, c1, c2, c3;
};

__device__ __forceinline__ void load_tw(const float2* __restrict__ W256f, int lane, TW& t) {
  t.a1 = W256f[lane];     t.a2 = W256f[2 * lane];  t.a3 = W256f[3 * lane];
  int p1 = 4 * (lane >> 2);
  t.b1 = W256f[p1];       t.b2 = W256f[2 * p1];    t.b3 = W256f[3 * p1];
  int p2 = 16 * (lane >> 4);
  t.c1 = W256f[p2];       t.c2 = W256f[2 * p2];    t.c3 = W256f[3 * p2];
}

// 256-pt forward complex FFT. Input regs z0..z3 = z[lane+64m]; output regs
// z0..z3 = Z[lane+64m]. Stages 0 & 3 in registers; 1 & 2 via wave-private LDS.
__device__ __forceinline__ void fft256_reg(float2& z0, float2& z1, float2& z2, float2& z3,
                                           float2* __restrict__ buf, int lane, const TW& tw) {
  float2 y0, t1, t2, t3;
  // stage 0 (s=1, p=lane): pure register butterfly, scatter 4l..4l+3
  r4bf(z0, z1, z2, z3, y0, t1, t2, t3);
  int o0 = 4 * lane;
  buf[SWZ(o0)]     = y0;
  buf[SWZ(o0 + 1)] = cmul(tw.a1, t1);
  buf[SWZ(o0 + 2)] = cmul(tw.a2, t2);
  buf[SWZ(o0 + 3)] = cmul(tw.a3, t3);
  wave_sync();
  // stage 1 (s=4)
  {
    float2 a = buf[SWZ(lane)], b = buf[SWZ(lane + 64)],
           c = buf[SWZ(lane + 128)], d = buf[SWZ(lane + 192)];
    wave_sync();
    r4bf(a, b, c, d, y0, t1, t2, t3);
    int o = lane + 12 * (lane >> 2);
    buf[SWZ(o)]      = y0;
    buf[SWZ(o + 4)]  = cmul(tw.b1, t1);
    buf[SWZ(o + 8)]  = cmul(tw.b2, t2);
    buf[SWZ(o + 12)] = cmul(tw.b3, t3);
  }
  wave_sync();
  // stage 2 (s=16)
  {
    float2 a = buf[SWZ(lane)], b = buf[SWZ(lane + 64)],
           c = buf[SWZ(lane + 128)], d = buf[SWZ(lane + 192)];
    wave_sync();
    r4bf(a, b, c, d, y0, t1, t2, t3);
    int o = lane + 48 * (lane >> 4);
    buf[SWZ(o)]      = y0;
    buf[SWZ(o + 16)] = cmul(tw.c1, t1);
    buf[SWZ(o + 32)] = cmul(tw.c2, t2);
    buf[SWZ(o + 48)] = cmul(tw.c3, t3);
  }
  wave_sync();
  // stage 3 (s=64, p=0, twiddle-free): outputs land in register layout
  {
    float2 a = buf[SWZ(lane)], b = buf[SWZ(lane + 64)],
           c = buf[SWZ(lane + 128)], d = buf[SWZ(lane + 192)];
    wave_sync();
    r4bf(a, b, c, d, z0, z1, z2, z3);
  }
}

// W256f[m] = exp(-2pi i m/256), m<256 ; W512s[k] = exp(-2pi i k/512), k<=256
__device__ __forceinline__ void build_tables(float2* W256f, float2* W512s) {
  int tid = threadIdx.x;
  float sv, cv;
  __sincosf(-(TWOPI / 256.0f) * (float)tid, &sv, &cv);
  W256f[tid] = make_float2(cv, sv);
  __sincosf(-(TWOPI / 512.0f) * (float)tid, &sv, &cv);
  W512s[tid] = make_float2(cv, sv);
  if (tid == 0) W512s[256] = make_float2(-1.f, 0.f);
}

// ---------------------------------------------------------------------------
// 1) channel mix: y[b,d,t] = sum_c x[b,c,t] * mixer[c,d]   (fp16 output)
//    2 samples/thread; no x LDS staging (no cross-thread reuse; loads are
//    naturally coalesced per channel).
// ---------------------------------------------------------------------------
__global__ __launch_bounds__(256) void mix_kernel(const float* __restrict__ x,
                                                  const float* __restrict__ mixer,
                                                  __half2* __restrict__ y) {
  __shared__ float mm[NCH][NCH];
  for (int i = threadIdx.x; i < NCH * NCH; i += 256)
    ((float*)mm)[i] = mixer[i];
  __syncthreads();
  int b = blockIdx.y;
  int t2 = blockIdx.x * 256 + threadIdx.x;     // float2-pair index
  const float2* xv = (const float2*)x;
  float2 xr[NCH];
#pragma unroll
  for (int c = 0; c < NCH; c++)
    xr[c] = xv[(((size_t)(b * NCH + c)) * T_LEN >> 1) + t2];
#pragma unroll 4
  for (int d = 0; d < NCH; d++) {
    float ax = 0.f, ay = 0.f;
#pragma unroll
    for (int c = 0; c < NCH; c++) {
      ax = fmaf(xr[c].x, mm[c][d], ax);
      ay = fmaf(xr[c].y, mm[c][d], ay);
    }
    y[(((size_t)(b * NCH + d)) * T_LEN >> 1) + t2] = f2h(make_float2(ax, ay));
  }
}

// ---------------------------------------------------------------------------
// 2) forward rfft(512) + register-local scan. Wave = one 4-frame chunk.
//    y and spec in fp16.
// ---------------------------------------------------------------------------
__global__ __launch_bounds__(256) void fft_fwd_kernel(const __half2* __restrict__ y,
                                                      const float* __restrict__ transfer,
                                                      __half2* __restrict__ spec) {
  __shared__ float2 fbuf[FPB][NBIN];     // wave-private FFT/mirror buffer
  __shared__ float2 W256f[256];
  __shared__ float2 W512s[NBIN];
  build_tables(W256f, W512s);
  __syncthreads();
  int wave = threadIdx.x >> 6, lane = threadIdx.x & 63;
  int cid = blockIdx.x * FPB + wave;     // chunk id 0..16383
  int bc = cid >> 7, blk = cid & (NBLK - 1);
  int ch = bc & (NCH - 1);
  float2* buf = fbuf[wave];
  TW tw; load_tw(W256f, lane, tw);
  // frame-invariant per-bin constants, k = lane + 64q
  float cwq[4], swq[4], trq[4];
#pragma unroll
  for (int q = 0; q < 4; q++) {
    int k = lane + 64 * q;
    cwq[q] = W512s[k].x; swq[q] = W512s[k].y;
    trq[q] = transfer[ch * NBIN + k];
  }
  float tr256 = transfer[ch * NBIN + 256];
  float2 s[4] = {make_float2(0,0), make_float2(0,0), make_float2(0,0), make_float2(0,0)};
  float s256x = 0.f;
  size_t base2 = ((size_t)bc * T_LEN + (size_t)blk * (FPB * HOP)) >> 1;  // half2 idx
  size_t fb = ((size_t)bc * NFR + (size_t)blk * FPB) * NBIN;
  bool lastchunk = (blk == NBLK - 1);
#pragma unroll
  for (int j = 0; j < FPB; j++) {
    const __half2* src = y + base2 + (size_t)j * (HOP / 2);
    // pack: z[n] = (y[2n], y[2n+1]) for n = lane+64q — one half2 load each
    float2 z0 = h2f(src[lane]);
    float2 z1 = h2f(src[lane + 64]);
    float2 z2, z3;
    if (lastchunk && j == FPB - 1) {     // zero-padded final half-window
      z2 = make_float2(0, 0); z3 = make_float2(0, 0);
    } else {
      z2 = h2f(src[lane + 128]);
      z3 = h2f(src[lane + 192]);
    }
    fft256_reg(z0, z1, z2, z3, buf, lane, tw);
    // stage Z (regs) for mirror access
    buf[lane] = z0; buf[lane + 64] = z1; buf[lane + 128] = z2; buf[lane + 192] = z3;
    wave_sync();
    float2 zm0 = buf[(256 - lane) & 255];
    float2 zm1 = buf[192 - lane];
    float2 zm2 = buf[128 - lane];
    float2 zm3 = buf[64 - lane];
    float2 z0b = buf[0];
    wave_sync();
    // untangle + scan + store, k = lane + 64q
#pragma unroll
    for (int q = 0; q < 4; q++) {
      float2 zk  = (q == 0) ? z0 : (q == 1) ? z1 : (q == 2) ? z2 : z3;
      float2 zmk = (q == 0) ? zm0 : (q == 1) ? zm1 : (q == 2) ? zm2 : zm3;
      float Ex = 0.5f * (zk.x + zmk.x), Ey = 0.5f * (zk.y - zmk.y);
      float dx = 0.5f * (zk.x - zmk.x), dy = 0.5f * (zk.y + zmk.y);
      float Ox = dy, Oy = -dx;
      float Yx = Ex + Ox * cwq[q] - Oy * swq[q];
      float Yy = Ey + Ox * swq[q] + Oy * cwq[q];
      s[q].x = trq[q] * (Yx + s[q].x);
      s[q].y = trq[q] * (Yy + s[q].y);
      spec[fb + (size_t)j * NBIN + lane + 64 * q] = f2h(s[q]);
    }
    // bin 256: zk = zmk = Z[0], cw=-1, sw=0 -> Y = (Z0.x - Z0.y, 0)
    s256x = tr256 * ((z0b.x - z0b.y) + s256x);
    if (lane == 0) spec[fb + (size_t)j * NBIN + 256] = f2h(make_float2(s256x, 0.f));
    wave_sync();
  }
}

// ---------------------------------------------------------------------------
// 3) carry scan across chunks: C[0]=0; C[i] = final[i-1] + tr^FPB * C[i-1]
// ---------------------------------------------------------------------------
__global__ __launch_bounds__(256) void carry_kernel(const __half2* __restrict__ spec,
                                                    const float* __restrict__ transfer,
                                                    __half2* __restrict__ carries) {
  int tid = blockIdx.x * 256 + threadIdx.x;
  if (tid >= NBC * NBIN) return;
  int bc = tid / NBIN, k = tid - bc * NBIN;
  int ch = bc & (NCH - 1);
  float tr = transfer[ch * NBIN + k];
  float tr2 = tr * tr;
  float tr4 = tr2 * tr2;          // tr^FPB
  const __half2* fin = spec + (size_t)bc * NFR * NBIN + (size_t)(FPB - 1) * NBIN + k;
  __half2* cp = carries + (size_t)bc * NBLK * NBIN + k;
  float cx = 0.f, cy = 0.f;
  for (int i = 0; i < NBLK; i += 8) {
    float2 v[8];
#pragma unroll
    for (int u = 0; u < 8; u++) v[u] = h2f(fin[(size_t)(i + u) * FPB * NBIN]);
#pragma unroll
    for (int u = 0; u < 8; u++) {
      cp[(size_t)(i + u) * NBIN] = f2h(make_float2(cx, cy));
      cx = v[u].x + tr4 * cx;
      cy = v[u].y + tr4 * cy;
    }
  }
}

// ---------------------------------------------------------------------------
// 4) inverse rfft + hann + register OLA. Wave = one 4-frame chunk.
//    spec/carries/bnd in fp16; out in fp32.
// ---------------------------------------------------------------------------
__global__ __launch_bounds__(256) void fft_inv_kernel(const __half2* __restrict__ spec,
                                                      const __half2* __restrict__ carries,
                                                      const float* __restrict__ transfer,
                                                      const float* __restrict__ gain,
                                                      float* __restrict__ out,
                                                      __half2* __restrict__ bnd) {
  __shared__ float2 fbuf[FPB][NBIN];
  __shared__ float2 W256f[256];
  __shared__ float2 W512s[NBIN];
  build_tables(W256f, W512s);
  __syncthreads();
  int wave = threadIdx.x >> 6, lane = threadIdx.x & 63;
  int cid = blockIdx.x * FPB + wave;
  int bc = cid >> 7, blk = cid & (NBLK - 1);
  int ch = bc & (NCH - 1);
  float2* buf = fbuf[wave];
  TW tw; load_tw(W256f, lane, tw);
  const __half2* crp = carries + ((size_t)bc * NBLK + blk) * NBIN;
  float cwq[4], swq[4], trq[4], trp[4], h0[4], h1[4];
  float2 cv[4];
#pragma unroll
  for (int q = 0; q < 4; q++) {
    int k = lane + 64 * q;
    cwq[q] = W512s[k].x; swq[q] = -W512s[k].y;   // exp(+2pi i k/512)
    trq[q] = transfer[ch * NBIN + k];
    trp[q] = trq[q];
    cv[q] = h2f(crp[k]);
    int t0 = 2 * k, t1 = 2 * k + 1;
    int i0 = (t0 <= 256) ? t0 : 512 - t0;
    int i1 = (t1 <= 256) ? t1 : 512 - t1;
    h0[q] = (0.5f - 0.5f * W512s[i0].x) * (1.0f / 256.0f);
    h1[q] = (0.5f - 0.5f * W512s[i1].x) * (1.0f / 256.0f);
  }
  float tr256 = transfer[ch * NBIN + 256], trp256 = tr256;
  float2 cv256 = h2f(crp[256]);
  float g = gain[ch];
  const __half2* sp0 = spec + ((size_t)bc * NFR + (size_t)blk * FPB) * NBIN;
  float2* outv = (float2*)out;
  size_t obase2 = ((size_t)bc * T_LEN + (size_t)blk * (FPB * HOP)) >> 1;
  __half2* bp = bnd + (((size_t)bc * NBLK + blk) * 2) * (HOP / 2);
  float2 pt0, pt1;                        // previous frame's windowed tail
#pragma unroll
  for (int j = 0; j < FPB; j++) {
    const __half2* sp = sp0 + (size_t)j * NBIN;
    // load + carry fix-up: O = local + tr^(j+1) * carry
    float2 Y0 = h2f(sp[lane]);       Y0.x = fmaf(trp[0], cv[0].x, Y0.x); Y0.y = fmaf(trp[0], cv[0].y, Y0.y);
    float2 Y1 = h2f(sp[lane + 64]);  Y1.x = fmaf(trp[1], cv[1].x, Y1.x); Y1.y = fmaf(trp[1], cv[1].y, Y1.y);
    float2 Y2 = h2f(sp[lane + 128]); Y2.x = fmaf(trp[2], cv[2].x, Y2.x); Y2.y = fmaf(trp[2], cv[2].y, Y2.y);
    float2 Y3 = h2f(sp[lane + 192]); Y3.x = fmaf(trp[3], cv[3].x, Y3.x); Y3.y = fmaf(trp[3], cv[3].y, Y3.y);
    float2 y256 = h2f(sp[256]);
    y256.x = fmaf(trp256, cv256.x, y256.x);
    y256.y = fmaf(trp256, cv256.y, y256.y);
#pragma unroll
    for (int q = 0; q < 4; q++) trp[q] *= trq[q];
    trp256 *= tr256;
    // mirror staging
    buf[lane] = Y0; buf[lane + 64] = Y1; buf[lane + 128] = Y2; buf[lane + 192] = Y3;
    if (lane == 0) buf[256] = y256;
    wave_sync();
    float2 ym0 = buf[256 - lane];
    float2 ym1 = buf[192 - lane];
    float2 ym2 = buf[128 - lane];
    float2 ym3 = buf[64 - lane];
    wave_sync();
    // inverse untangle -> conj'd FFT input (register layout k = lane+64q)
    float2 z0, z1, z2, z3;
#pragma unroll
    for (int q = 0; q < 4; q++) {
      float2 yk  = (q == 0) ? Y0 : (q == 1) ? Y1 : (q == 2) ? Y2 : Y3;
      float2 ymk = (q == 0) ? ym0 : (q == 1) ? ym1 : (q == 2) ? ym2 : ym3;
      float Ex = 0.5f * (yk.x + ymk.x), Ey = 0.5f * (yk.y - ymk.y);
      float dx = 0.5f * (yk.x - ymk.x), dy = 0.5f * (yk.y + ymk.y);
      float Ox = dx * cwq[q] - dy * swq[q];
      float Oy = dx * swq[q] + dy * cwq[q];
      float2 zq = make_float2(Ex - Oy, -(Ey + Ox));
      if (q == 0) z0 = zq; else if (q == 1) z1 = zq; else if (q == 2) z2 = zq; else z3 = zq;
    }
    fft256_reg(z0, z1, z2, z3, buf, lane, tw);
    // windowed time samples: s = 2n, 2n+1 at n = lane+64q; x = conj/256
    float2 w0 = make_float2(z0.x * h0[0], -z0.y * h1[0]);
    float2 w1 = make_float2(z1.x * h0[1], -z1.y * h1[1]);
    float2 w2 = make_float2(z2.x * h0[2], -z2.y * h1[2]);
    float2 w3 = make_float2(z3.x * h0[3], -z3.y * h1[3]);
    if (j == 0) {
      bp[lane]      = f2h(w0);            // chunk-leading head -> bnd
      bp[lane + 64] = f2h(w1);
    } else {
      float2 v0 = make_float2(pt0.x + w0.x, pt0.y + w0.y);
      float2 v1 = make_float2(pt1.x + w1.x, pt1.y + w1.y);
      outv[obase2 + (size_t)j * 128 + lane] =
          make_float2(fast_tanh(g * v0.x), fast_tanh(g * v0.y));
      outv[obase2 + (size_t)j * 128 + lane + 64] =
          make_float2(fast_tanh(g * v1.x), fast_tanh(g * v1.y));
    }
    pt0 = w2; pt1 = w3;
    wave_sync();
  }
  bp[128 + lane] = f2h(pt0);              // chunk-trailing tail -> bnd
  bp[192 + lane] = f2h(pt1);
}

// ---------------------------------------------------------------------------
// 5) combine boundary chunks: chunk FPB*b <- bnd[b-1].tail + bnd[b].head
// ---------------------------------------------------------------------------
__global__ __launch_bounds__(256) void final_kernel(const __half* __restrict__ bnd,
                                                    const float* __restrict__ gain,
                                                    float* __restrict__ out) {
  int bc = blockIdx.y, b = blockIdx.x;
  int s = threadIdx.x;
  const __half* base = bnd + ((size_t)bc * NBLK) * 2 * HOP;
  float v = __half2float(base[((size_t)b * 2) * HOP + s]);
  if (b > 0) v += __half2float(base[((size_t)(b - 1) * 2 + 1) * HOP + s]);
  float g = gain[bc & (NCH - 1)];
  out[(size_t)bc * T_LEN + (size_t)b * (FPB * HOP) + s] = fast_tanh(g * v);
}

// ---------------------------------------------------------------------------
extern "C" void kernel_launch(void* const* d_in, const int* in_sizes, int n_in,
                              void* d_out, int out_size, void* d_ws, size_t ws_size,
                              hipStream_t stream) {
  (void)in_sizes; (void)n_in; (void)out_size; (void)ws_size;
  const float* x        = (const float*)d_in[0];
  const float* transfer = (const float*)d_in[1];
  const float* mixer    = (const float*)d_in[2];
  const float* gain     = (const float*)d_in[3];
  float* out = (float*)d_out;

  // ws layout (all fp16 now, no aliasing needed):
  //  [spec 67,371,008 B][bnd 16,777,216 B][carries 16,842,752 B][y 33,554,432 B]
  char* p = (char*)d_ws;
  __half2* spec    = (__half2*)p;                       p += (size_t)NBC * NFR * NBIN * 4;
  __half2* bnd     = (__half2*)p;                       p += (size_t)NBC * NBLK * 2 * HOP * 2;
  __half2* carries = (__half2*)p;                       p += (size_t)NBC * NBLK * NBIN * 4;
  __half2* y       = (__half2*)p;

  mix_kernel<<<dim3(T_LEN / 512, NBAT), 256, 0, stream>>>(x, mixer, y);
  fft_fwd_kernel<<<dim3(NBC * NBLK / FPB), 256, 0, stream>>>(y, transfer, spec);
  carry_kernel<<<dim3((NBC * NBIN + 255) / 256), 256, 0, stream>>>(spec, transfer, carries);
  fft_inv_kernel<<<dim3(NBC * NBLK / FPB), 256, 0, stream>>>(spec, carries, transfer, gain, out, (__half2*)bnd);
  final_kernel<<<dim3(NBLK, NBC), 256, 0, stream>>>((const __half*)bnd, gain, out);
}